// Round 3
// baseline (1047.717 us; speedup 1.0000x reference)
//
#include <hip/hip_runtime.h>
#include <hip/hip_bf16.h>
#include <math.h>

// ---------------- constants ----------------
#define BSZ     2
#define TLEN    4096
#define DMODEL  1024
#define DINNER  2048
#define DSTATE  64
#define NHEADS  32
#define HEADDIM 64
#define CHUNK   64
#define NCHUNK  64            // TLEN / CHUNK
#define CONVDIM 2176          // DINNER + 2*DSTATE
#define DPROJ   4256          // 2*DINNER + 2*DSTATE + NHEADS
#define ROWS    8192          // BSZ*TLEN

typedef __attribute__((ext_vector_type(8))) short s16x8;
typedef __attribute__((ext_vector_type(4))) float f32x4;

__device__ __forceinline__ float bf2f(__hip_bfloat16 x) { return __bfloat162float(x); }
__device__ __forceinline__ __hip_bfloat16 f2bf(float x) { return __float2bfloat16(x); }
__device__ __forceinline__ short f2bf_s(float x) {
  union { __hip_bfloat16 h; short s; } c; c.h = __float2bfloat16(x); return c.s;
}

// ---------------- f32 -> bf16 cast ----------------
__global__ __launch_bounds__(256) void cast_f32_bf16(
    const float* __restrict__ src, __hip_bfloat16* __restrict__ dst, int n) {
  const int i = (blockIdx.x * 256 + threadIdx.x) * 4;
  if (i + 3 < n) {
    const f32x4 v = *(const f32x4*)(src + i);
    dst[i + 0] = f2bf(v[0]); dst[i + 1] = f2bf(v[1]);
    dst[i + 2] = f2bf(v[2]); dst[i + 3] = f2bf(v[3]);
  } else {
    for (int j = i; j < n; ++j) dst[j] = f2bf(src[j]);
  }
}

// ---------------- GEMM: C = A[M][K] @ B[N][K]^T  (f32 acc) ----------------
// MODE=1 (in-proj): A is f32 (converted in-register), output split:
//   cols [0,2048)->Cz bf16 ld 2048, [2048,4224)->Cx bf16 ld 2176, [4224,4256)->Cd f32 ld 32.
// MODE=0 (out-proj): A is bf16, output Cout f32 ld N.
template <int MODE>
__global__ __launch_bounds__(256) void gemm_nt(
    const void* __restrict__ Avoid, const __hip_bfloat16* __restrict__ B,
    __hip_bfloat16* __restrict__ Cz, __hip_bfloat16* __restrict__ Cx,
    float* __restrict__ Cd, float* __restrict__ Cout, int M, int N, int K) {
  const int wave = threadIdx.x >> 6;
  const int lane = threadIdx.x & 63;
  const int lhi = lane >> 4;      // 0..3
  const int llo = lane & 15;      // 0..15
  const int m_base = blockIdx.x * 256 + wave * 64;
  const int n_base = blockIdx.y * 64;

  const float* Af = (const float*)Avoid;
  const short* Ap = (const short*)Avoid;
  const short* Bp = (const short*)B;

  f32x4 acc[4][4];
  const f32x4 fz = {0.f, 0.f, 0.f, 0.f};
#pragma unroll
  for (int mi = 0; mi < 4; ++mi)
#pragma unroll
    for (int ni = 0; ni < 4; ++ni) acc[mi][ni] = fz;

  const s16x8 zer = {0, 0, 0, 0, 0, 0, 0, 0};
  for (int k0 = 0; k0 < K; k0 += 32) {
    const int kk = k0 + lhi * 8;
    s16x8 af[4], bfr[4];
#pragma unroll
    for (int i = 0; i < 4; ++i) {
      const int arow = m_base + i * 16 + llo;            // always < M (M % 256 == 0)
      if (MODE == 1) {
        const float* p = Af + (size_t)arow * K + kk;
        const f32x4 lo = *(const f32x4*)p;
        const f32x4 hi = *(const f32x4*)(p + 4);
        s16x8 t;
        t[0] = f2bf_s(lo[0]); t[1] = f2bf_s(lo[1]); t[2] = f2bf_s(lo[2]); t[3] = f2bf_s(lo[3]);
        t[4] = f2bf_s(hi[0]); t[5] = f2bf_s(hi[1]); t[6] = f2bf_s(hi[2]); t[7] = f2bf_s(hi[3]);
        af[i] = t;
      } else {
        af[i] = *(const s16x8*)(Ap + (size_t)arow * K + kk);
      }
      const int bcol = n_base + i * 16 + llo;
      bfr[i] = (bcol < N) ? *(const s16x8*)(Bp + (size_t)bcol * K + kk) : zer;
    }
#pragma unroll
    for (int mi = 0; mi < 4; ++mi)
#pragma unroll
      for (int ni = 0; ni < 4; ++ni)
        acc[mi][ni] = __builtin_amdgcn_mfma_f32_16x16x32_bf16(af[mi], bfr[ni], acc[mi][ni], 0, 0, 0);
  }

#pragma unroll
  for (int mi = 0; mi < 4; ++mi)
#pragma unroll
    for (int ni = 0; ni < 4; ++ni)
#pragma unroll
      for (int r = 0; r < 4; ++r) {
        const int row = m_base + mi * 16 + lhi * 4 + r;   // C/D: col=lane&15, row=(lane>>4)*4+r
        const int col = n_base + ni * 16 + llo;
        if (col >= N) continue;
        const float v = acc[mi][ni][r];
        if (MODE == 1) {
          if (col < DINNER)                Cz[(size_t)row * DINNER + col] = f2bf(v);
          else if (col < DINNER + CONVDIM) Cx[(size_t)row * CONVDIM + (col - DINNER)] = f2bf(v);
          else                             Cd[(size_t)row * NHEADS + (col - DINNER - CONVDIM)] = v;
        } else {
          Cout[(size_t)row * N + col] = v;
        }
      }
}

// ---------------- conv1d (depthwise, causal, width 4) + SiLU ----------------
__global__ __launch_bounds__(256) void conv_silu_kernel(
    const __hip_bfloat16* __restrict__ xBC, const float* __restrict__ conv_w,
    const float* __restrict__ conv_b, __hip_bfloat16* __restrict__ convOut) {
  const int idx = blockIdx.x * 256 + threadIdx.x;     // (b*TLEN+t)*CONVDIM + c
  if (idx >= ROWS * CONVDIM) return;
  const int c  = idx % CONVDIM;
  const int bt = idx / CONVDIM;
  const int t  = bt & (TLEN - 1);
  const int b  = bt >> 12;
  float acc = conv_b[c];
#pragma unroll
  for (int k = 0; k < 4; ++k) {
    const int tt = t - 3 + k;
    if (tt >= 0)
      acc += conv_w[c * 4 + k] *
             bf2f(xBC[((size_t)(b * TLEN + tt)) * CONVDIM + c]);
  }
  const float s = acc / (1.f + expf(-acc));
  convOut[(size_t)bt * CONVDIM + c] = f2bf(s);
}

// ---------------- dt = softplus(dt_raw + bias); cum = per-chunk cumsum(A*dt) ----------------
__global__ __launch_bounds__(256) void dt_cumsum_kernel(
    const float* __restrict__ dt_raw, const float* __restrict__ dt_bias,
    const float* __restrict__ A_log, float* __restrict__ dt_sp, float* __restrict__ cum) {
  const int idx = blockIdx.x * 256 + threadIdx.x;     // (b*NHEADS+h)*NCHUNK + c
  if (idx >= BSZ * NHEADS * NCHUNK) return;
  const int c  = idx & 63;
  const int bh = idx >> 6;
  const int h  = bh & 31;
  const int b  = bh >> 5;
  const float bias = dt_bias[h];
  const float A = -expf(A_log[h]);
  float run = 0.f;
  for (int l = 0; l < CHUNK; ++l) {
    const int t = c * CHUNK + l;
    const float raw = dt_raw[((size_t)(b * TLEN + t)) * NHEADS + h] + bias;
    const float d = (raw > 20.f) ? raw : log1pf(expf(raw));
    run += A * d;
    dt_sp[(size_t)bh * TLEN + t] = d;
    cum[(size_t)bh * TLEN + t] = run;
  }
}

// ---------------- per-chunk state: cs[b][c][h][p][n] = sum_l B[l][n]*exp(cumL-cum[l])*x[l][p]*dt[l] ----------------
__global__ __launch_bounds__(256) void chunk_state_kernel(
    const __hip_bfloat16* __restrict__ convOut, const float* __restrict__ dt_sp,
    const float* __restrict__ cum, __hip_bfloat16* __restrict__ chunk_states) {
  __shared__ float sB[64][65];   // B[l][n]
  __shared__ float sW[64][65];   // x[l][p]*dt[l]*exp(cumL-cum[l])
  const int c = blockIdx.x, h = blockIdx.y, b = blockIdx.z;
  const int tid = threadIdx.x;
  const int bh = b * NHEADS + h;
  const float cumL = cum[(size_t)bh * TLEN + c * CHUNK + 63];
  for (int i = tid; i < 4096; i += 256) {
    const int l = i >> 6, j = i & 63;
    const size_t rowoff = ((size_t)(b * TLEN + c * CHUNK + l)) * CONVDIM;
    sB[l][j] = bf2f(convOut[rowoff + DINNER + j]);
    const float d = dt_sp[(size_t)bh * TLEN + c * CHUNK + l];
    const float dec = expf(cumL - cum[(size_t)bh * TLEN + c * CHUNK + l]);
    sW[l][j] = bf2f(convOut[rowoff + h * HEADDIM + j]) * d * dec;
  }
  __syncthreads();
  const int n = tid & 63, pg = tid >> 6;   // p = pg*16 + i
  float acc[16];
#pragma unroll
  for (int i = 0; i < 16; ++i) acc[i] = 0.f;
  for (int l = 0; l < 64; ++l) {
    const float bv = sB[l][n];
#pragma unroll
    for (int i = 0; i < 16; ++i) acc[i] += sW[l][pg * 16 + i] * bv;
  }
  const size_t outb = ((((size_t)b * NCHUNK + c) * NHEADS + h) * HEADDIM) * DSTATE;
#pragma unroll
  for (int i = 0; i < 16; ++i)
    chunk_states[outb + (size_t)(pg * 16 + i) * DSTATE + n] = f2bf(acc[i]);
}

// ---------------- inter-chunk scan, IN-PLACE: cs[c] <- state BEFORE chunk c ----------------
__global__ __launch_bounds__(256) void scan_kernel(
    __hip_bfloat16* __restrict__ cs, const float* __restrict__ cum) {
  const int idx = blockIdx.x * 256 + threadIdx.x;   // ((b*32+h)*64+p)*64+n
  const int n = idx & 63;
  int r = idx >> 6;
  const int p = r & 63; r >>= 6;
  const int h = r & 31;
  const int b = r >> 5;
  const int bh = b * NHEADS + h;
  const size_t stride_c = (size_t)NHEADS * HEADDIM * DSTATE;
  const size_t base = ((size_t)b * NCHUNK) * stride_c + ((size_t)h * HEADDIM + p) * DSTATE + n;
  float s = 0.f;
  for (int c = 0; c < NCHUNK; ++c) {
    const size_t off = base + (size_t)c * stride_c;
    const float val = bf2f(cs[off]);           // read chunk-state BEFORE overwrite
    cs[off] = f2bf(s);                         // write pre-state (exclusive scan)
    const float dec = expf(cum[(size_t)bh * TLEN + c * CHUNK + 63]);
    s = dec * s + val;
  }
}

// ---------------- per-chunk output: Yraw[b][t][h*64+p]  (bf16) ----------------
__global__ __launch_bounds__(256) void y_kernel(
    const __hip_bfloat16* __restrict__ convOut, const float* __restrict__ dt_sp,
    const float* __restrict__ cum, const __hip_bfloat16* __restrict__ states_pre,
    const float* __restrict__ Dparam, __hip_bfloat16* __restrict__ Yraw) {
  __shared__ __hip_bfloat16 sC[64][64];  // C[l][n]   (broadcast reads only)
  __shared__ float sX[64][64];           // x[s][p]*dt[s] (reads lane-consecutive col)
  __shared__ float sBSP[64][65];         // phase1: B[s][n]; phase2: SP[p][n]
  __shared__ float sG[64][64];           // G[l][s] then W[l][s]
  __shared__ float scum[64];
  const int c = blockIdx.x, h = blockIdx.y, b = blockIdx.z;
  const int tid = threadIdx.x;
  const int bh = b * NHEADS + h;
  const size_t tbase = (size_t)(b * TLEN + c * CHUNK);

  for (int i = tid; i < 4096; i += 256) {
    const int l = i >> 6, j = i & 63;
    const size_t rowoff = (tbase + l) * CONVDIM;
    sC[l][j] = convOut[rowoff + DINNER + DSTATE + j];
    sBSP[l][j] = bf2f(convOut[rowoff + DINNER + j]);
    sX[l][j] = bf2f(convOut[rowoff + h * HEADDIM + j]) * dt_sp[(size_t)bh * TLEN + c * CHUNK + l];
  }
  if (tid < 64) scum[tid] = cum[(size_t)bh * TLEN + c * CHUNK + tid];
  __syncthreads();

  // phase 1: G[l][s] = sum_n C[l][n] * B[s][n]
  {
    const int s = tid & 63, lg = tid >> 6;
    float accG[16];
#pragma unroll
    for (int i = 0; i < 16; ++i) accG[i] = 0.f;
    for (int n = 0; n < 64; ++n) {
      const float bv = sBSP[s][n];
#pragma unroll
      for (int i = 0; i < 16; ++i) accG[i] += bf2f(sC[lg * 16 + i][n]) * bv;
    }
#pragma unroll
    for (int i = 0; i < 16; ++i) sG[lg * 16 + i][s] = accG[i];
  }
  __syncthreads();

  // phase 2: W[l][s] = (s<=l) ? G*exp(cum[l]-cum[s]) : 0 ; reload sBSP <- SP[p][n]
  for (int e = tid; e < 4096; e += 256) {
    const int l = e >> 6, s = e & 63;
    const float v = sG[l][s];
    sG[l][s] = (s <= l) ? v * expf(scum[l] - scum[s]) : 0.f;
  }
  const size_t spbase = ((((size_t)b * NCHUNK + c) * NHEADS + h) * HEADDIM) * DSTATE;
  for (int i = tid; i < 4096; i += 256) {
    const int p = i >> 6, j = i & 63;
    sBSP[p][j] = bf2f(states_pre[spbase + (size_t)p * DSTATE + j]);
  }
  __syncthreads();

  // phase 3: Y[l][p] = sum_s W[l][s]*xdt[s][p] + exp(cum[l]) * sum_n C[l][n]*SP[p][n] + D*x
  const int p = tid & 63, lg = tid >> 6;
  float accD[16], accO[16];
#pragma unroll
  for (int i = 0; i < 16; ++i) { accD[i] = 0.f; accO[i] = 0.f; }
  for (int s = 0; s < 64; ++s) {
    const float xv = sX[s][p];
    const float spv = sBSP[p][s];
#pragma unroll
    for (int i = 0; i < 16; ++i) {
      const int l = lg * 16 + i;
      accD[i] += sG[l][s] * xv;
      accO[i] += bf2f(sC[l][s]) * spv;
    }
  }
  const float Dh = Dparam[h];
#pragma unroll
  for (int i = 0; i < 16; ++i) {
    const int l = lg * 16 + i;
    const size_t row = tbase + l;
    const float xval = bf2f(convOut[row * CONVDIM + h * HEADDIM + p]);
    Yraw[row * DINNER + h * HEADDIM + p] =
        f2bf(accD[i] + expf(scum[l]) * accO[i] + Dh * xval);
  }
}

// ---------------- gate (silu(z)) + RMSNorm -> bf16 ----------------
__global__ __launch_bounds__(256) void gate_norm_kernel(
    const __hip_bfloat16* __restrict__ Yraw, const __hip_bfloat16* __restrict__ z,
    const float* __restrict__ norm_w, __hip_bfloat16* __restrict__ ybf) {
  const int row = blockIdx.x;
  const int tid = threadIdx.x;
  const size_t base = (size_t)row * DINNER + tid * 8;
  float vals[8];
  float ss = 0.f;
#pragma unroll
  for (int j = 0; j < 8; ++j) {
    const float yv = bf2f(Yraw[base + j]);
    const float zv = bf2f(z[base + j]);
    const float g = zv / (1.f + expf(-zv));
    const float v = yv * g;
    vals[j] = v;
    ss += v * v;
  }
  __shared__ float red[256];
  red[tid] = ss;
  __syncthreads();
  for (int s = 128; s > 0; s >>= 1) {
    if (tid < s) red[tid] += red[tid + s];
    __syncthreads();
  }
  const float rms = rsqrtf(red[0] / (float)DINNER + 1e-5f);
#pragma unroll
  for (int j = 0; j < 8; ++j) {
    const float nw = norm_w[tid * 8 + j];
    ybf[base + j] = f2bf(vals[j] * rms * nw);
  }
}

// ---------------- launch ----------------
extern "C" void kernel_launch(void* const* d_in, const int* in_sizes, int n_in,
                              void* d_out, int out_size, void* d_ws, size_t ws_size,
                              hipStream_t stream) {
  const float* u       = (const float*)d_in[0];
  const float* W_in    = (const float*)d_in[1];
  const float* conv_w  = (const float*)d_in[2];
  const float* conv_b  = (const float*)d_in[3];
  const float* dt_bias = (const float*)d_in[4];
  const float* A_log   = (const float*)d_in[5];
  const float* Dp      = (const float*)d_in[6];
  const float* norm_w  = (const float*)d_in[7];
  const float* W_out   = (const float*)d_in[8];
  float* out = (float*)d_out;

  // --- workspace overlay (peak 131,399,680 bytes; all offsets 16B-aligned) ---
  char* w = (char*)d_ws;
  const size_t OFF_WB   = 0;                                     // Win_bf: 4,358,144*2 = 8,716,288
  const size_t OFF_Z    = OFF_WB  + (size_t)DPROJ * DMODEL * 2;  // z bf16: 16,777,216
  const size_t OFF_XBC  = OFF_Z   + (size_t)ROWS * DINNER * 2;   // xBC bf16: 35,651,584 (reused: Yraw)
  const size_t OFF_DTR  = OFF_XBC + (size_t)ROWS * CONVDIM * 2;  // dt_raw f32: 1,048,576
  const size_t OFF_CONV = OFF_DTR + (size_t)ROWS * NHEADS * 4;   // convOut bf16: 35,651,584
  const size_t OFF_CS   = OFF_CONV+ (size_t)ROWS * CONVDIM * 2;  // cs bf16: 33,554,432 (reused: ybf)
  // Win_bf region reused after gemm1: Wout_bf (4,194,304) | dt_sp (1,048,576) | cum (1,048,576)
  const size_t OFF_WOB  = OFF_WB;
  const size_t OFF_DSP  = OFF_WB + (size_t)DMODEL * DINNER * 2;
  const size_t OFF_CUM  = OFF_DSP + (size_t)ROWS * NHEADS * 4;

  __hip_bfloat16* Win_bf  = (__hip_bfloat16*)(w + OFF_WB);
  __hip_bfloat16* Wout_bf = (__hip_bfloat16*)(w + OFF_WOB);
  __hip_bfloat16* Bz      = (__hip_bfloat16*)(w + OFF_Z);
  __hip_bfloat16* Bx      = (__hip_bfloat16*)(w + OFF_XBC);
  float*          Bd      = (float*)(w + OFF_DTR);
  __hip_bfloat16* Bconv   = (__hip_bfloat16*)(w + OFF_CONV);
  float*          dt_sp   = (float*)(w + OFF_DSP);
  float*          cum     = (float*)(w + OFF_CUM);
  __hip_bfloat16* Bcs     = (__hip_bfloat16*)(w + OFF_CS);
  __hip_bfloat16* Yraw    = Bx;    // xBC_raw dead after conv
  __hip_bfloat16* ybf     = Bcs;   // states dead after y_kernel

  // 0. cast W_in -> bf16
  cast_f32_bf16<<<(DPROJ * DMODEL / 4 + 255) / 256, 256, 0, stream>>>(W_in, Win_bf, DPROJ * DMODEL);
  // 1. in-projection (A=f32 u, converted in-register), split epilogue: z | xBC_raw | dt_raw
  gemm_nt<1><<<dim3(ROWS / 256, (DPROJ + 63) / 64), 256, 0, stream>>>(
      (const void*)u, Win_bf, Bz, Bx, Bd, nullptr, ROWS, DPROJ, DMODEL);
  // 0b. cast W_out -> bf16 (after gemm1: reuses Win_bf region)
  cast_f32_bf16<<<(DMODEL * DINNER / 4 + 255) / 256, 256, 0, stream>>>(W_out, Wout_bf, DMODEL * DINNER);
  // 2. causal depthwise conv + SiLU
  conv_silu_kernel<<<(ROWS * CONVDIM) / 256, 256, 0, stream>>>(Bx, conv_w, conv_b, Bconv);
  // 3. dt softplus + per-chunk cumsum of A*dt
  dt_cumsum_kernel<<<(BSZ * NHEADS * NCHUNK + 255) / 256, 256, 0, stream>>>(
      Bd, dt_bias, A_log, dt_sp, cum);
  // 4. per-chunk states (bf16)
  chunk_state_kernel<<<dim3(NCHUNK, NHEADS, BSZ), 256, 0, stream>>>(Bconv, dt_sp, cum, Bcs);
  // 5. inter-chunk exclusive scan, in-place
  scan_kernel<<<(BSZ * NHEADS * HEADDIM * DSTATE) / 256, 256, 0, stream>>>(Bcs, cum);
  // 6. Y = diag + off + D*x  -> Yraw (bf16, into dead xBC_raw buffer)
  y_kernel<<<dim3(NCHUNK, NHEADS, BSZ), 256, 0, stream>>>(Bconv, dt_sp, cum, Bcs, Dp, Yraw);
  // 7. gate + RMSNorm -> ybf (into dead chunk-state buffer)
  gate_norm_kernel<<<ROWS, 256, 0, stream>>>(Yraw, Bz, norm_w, ybf);
  // 8. out-projection -> f32 d_out
  gemm_nt<0><<<dim3(ROWS / 256, DMODEL / 64), 256, 0, stream>>>(
      (const void*)ybf, Wout_bf, nullptr, nullptr, nullptr, out, ROWS, DMODEL, DINNER);
}

// Round 4
// 723.741 us; speedup vs baseline: 1.4476x; 1.4476x over previous
//
#include <hip/hip_runtime.h>
#include <hip/hip_bf16.h>
#include <math.h>

// ---------------- constants ----------------
#define BSZ     2
#define TLEN    4096
#define DMODEL  1024
#define DINNER  2048
#define DSTATE  64
#define NHEADS  32
#define HEADDIM 64
#define CHUNK   64
#define NCHUNK  64            // TLEN / CHUNK
#define CONVDIM 2176          // DINNER + 2*DSTATE
#define DPROJ   4256          // 2*DINNER + 2*DSTATE + NHEADS
#define ROWS    8192          // BSZ*TLEN

typedef __attribute__((ext_vector_type(8))) short s16x8;
typedef __attribute__((ext_vector_type(4))) float f32x4;

__device__ __forceinline__ float bf2f(__hip_bfloat16 x) { return __bfloat162float(x); }
__device__ __forceinline__ __hip_bfloat16 f2bf(float x) { return __float2bfloat16(x); }

#define GLDS16(g, l)                                                        \
  __builtin_amdgcn_global_load_lds(                                         \
      (const __attribute__((address_space(1))) void*)(g),                   \
      (__attribute__((address_space(3))) void*)(l), 16, 0, 0)

// ---------------- f32 -> bf16 cast ----------------
__global__ __launch_bounds__(256) void cast_f32_bf16(
    const float* __restrict__ src, __hip_bfloat16* __restrict__ dst, int n) {
  const int i = (blockIdx.x * 256 + threadIdx.x) * 4;
  if (i + 3 < n) {
    const f32x4 v = *(const f32x4*)(src + i);
    dst[i + 0] = f2bf(v[0]); dst[i + 1] = f2bf(v[1]);
    dst[i + 2] = f2bf(v[2]); dst[i + 3] = f2bf(v[3]);
  } else {
    for (int j = i; j < n; ++j) dst[j] = f2bf(src[j]);
  }
}

// ---------------- LDS-tiled GEMM (m97 structure): C = A[M][K] @ B[N][K]^T ----------------
// 128x128 block tile, BK=32, 4 waves each 64x64 via 4x4 MFMA 16x16x32 frags.
// global_load_lds width=16 staging; ds_read_b128 fragment loads; f32 acc.
// SPLIT=1 (in-proj): cols [0,2048)->Cz bf16, [2048,4224)->Cx bf16, [4224,4256)->Cd f32. Masked at N.
// SPLIT=0 (out-proj): Cout f32 ld N.
template <int SPLIT>
__global__ __launch_bounds__(256) void gemm_tiled(
    const short* __restrict__ A, const short* __restrict__ B,
    __hip_bfloat16* __restrict__ Cz, __hip_bfloat16* __restrict__ Cx,
    float* __restrict__ Cd, float* __restrict__ Cout, int M, int N, int K) {
  __shared__ short sA[128 * 32];   // [row][k] row-major, stride 32, NO padding (global_load_lds contract)
  __shared__ short sB[128 * 32];
  const int tid  = threadIdx.x;
  const int wave = tid >> 6, lane = tid & 63;
  const int lhi  = lane >> 4, llo = lane & 15;
  const int wm   = wave >> 1, wn = wave & 1;
  const int tm   = blockIdx.x * 128, tn = blockIdx.y * 128;

  // staging map: within a 16-row (1 KB) segment, lane i -> row i/4, k-offset (i&3)*8 elems
  const int srow  = lane >> 2;
  const int skcol = (lane & 3) * 8;

  f32x4 acc[4][4];
  const f32x4 fz = {0.f, 0.f, 0.f, 0.f};
#pragma unroll
  for (int mi = 0; mi < 4; ++mi)
#pragma unroll
    for (int ni = 0; ni < 4; ++ni) acc[mi][ni] = fz;

  for (int k0 = 0; k0 < K; k0 += 32) {
#pragma unroll
    for (int it = 0; it < 2; ++it) {
      const int seg = it * 4 + wave;                       // 0..7 (16 rows each)
      const short* ga = A + (size_t)(tm + seg * 16 + srow) * K + k0 + skcol;
      GLDS16(ga, sA + seg * 512);
      const short* gb = B + (size_t)(tn + seg * 16 + srow) * K + k0 + skcol;
      GLDS16(gb, sB + seg * 512);
    }
    __syncthreads();                                       // drains vmcnt -> LDS valid
    s16x8 af[4], bfr[4];
#pragma unroll
    for (int i = 0; i < 4; ++i) {
      af[i]  = *(const s16x8*)(sA + (wm * 64 + i * 16 + llo) * 32 + lhi * 8);
      bfr[i] = *(const s16x8*)(sB + (wn * 64 + i * 16 + llo) * 32 + lhi * 8);
    }
#pragma unroll
    for (int mi = 0; mi < 4; ++mi)
#pragma unroll
      for (int ni = 0; ni < 4; ++ni)
        acc[mi][ni] = __builtin_amdgcn_mfma_f32_16x16x32_bf16(af[mi], bfr[ni], acc[mi][ni], 0, 0, 0);
    __syncthreads();                                       // protect LDS from next stage
  }

#pragma unroll
  for (int mi = 0; mi < 4; ++mi)
#pragma unroll
    for (int ni = 0; ni < 4; ++ni)
#pragma unroll
      for (int r = 0; r < 4; ++r) {
        const int row = tm + wm * 64 + mi * 16 + lhi * 4 + r;  // C/D: col=lane&15, row=(lane>>4)*4+r
        const int col = tn + wn * 64 + ni * 16 + llo;
        if (col >= N) continue;
        const float v = acc[mi][ni][r];
        if (SPLIT) {
          if (col < DINNER)                Cz[(size_t)row * DINNER + col] = f2bf(v);
          else if (col < DINNER + CONVDIM) Cx[(size_t)row * CONVDIM + (col - DINNER)] = f2bf(v);
          else                             Cd[(size_t)row * NHEADS + (col - DINNER - CONVDIM)] = v;
        } else {
          Cout[(size_t)row * N + col] = v;
        }
      }
}

// ---------------- conv1d (depthwise, causal, width 4) + SiLU ----------------
__global__ __launch_bounds__(256) void conv_silu_kernel(
    const __hip_bfloat16* __restrict__ xBC, const float* __restrict__ conv_w,
    const float* __restrict__ conv_b, __hip_bfloat16* __restrict__ convOut) {
  const int idx = blockIdx.x * 256 + threadIdx.x;     // (b*TLEN+t)*CONVDIM + c
  if (idx >= ROWS * CONVDIM) return;
  const int c  = idx % CONVDIM;
  const int bt = idx / CONVDIM;
  const int t  = bt & (TLEN - 1);
  const int b  = bt >> 12;
  float acc = conv_b[c];
#pragma unroll
  for (int k = 0; k < 4; ++k) {
    const int tt = t - 3 + k;
    if (tt >= 0)
      acc += conv_w[c * 4 + k] *
             bf2f(xBC[((size_t)(b * TLEN + tt)) * CONVDIM + c]);
  }
  const float s = acc / (1.f + expf(-acc));
  convOut[(size_t)bt * CONVDIM + c] = f2bf(s);
}

// ---------------- dt = softplus(dt_raw + bias); cum = per-chunk cumsum(A*dt) ----------------
__global__ __launch_bounds__(256) void dt_cumsum_kernel(
    const float* __restrict__ dt_raw, const float* __restrict__ dt_bias,
    const float* __restrict__ A_log, float* __restrict__ dt_sp, float* __restrict__ cum) {
  const int idx = blockIdx.x * 256 + threadIdx.x;     // (b*NHEADS+h)*NCHUNK + c
  if (idx >= BSZ * NHEADS * NCHUNK) return;
  const int c  = idx & 63;
  const int bh = idx >> 6;
  const int h  = bh & 31;
  const int b  = bh >> 5;
  const float bias = dt_bias[h];
  const float A = -expf(A_log[h]);
  float run = 0.f;
  for (int l = 0; l < CHUNK; ++l) {
    const int t = c * CHUNK + l;
    const float raw = dt_raw[((size_t)(b * TLEN + t)) * NHEADS + h] + bias;
    const float d = (raw > 20.f) ? raw : log1pf(expf(raw));
    run += A * d;
    dt_sp[(size_t)bh * TLEN + t] = d;
    cum[(size_t)bh * TLEN + t] = run;
  }
}

// ---------------- per-chunk state: cs[b][c][h][p][n] = sum_l B[l][n]*exp(cumL-cum[l])*x[l][p]*dt[l] ----------------
__global__ __launch_bounds__(256) void chunk_state_kernel(
    const __hip_bfloat16* __restrict__ convOut, const float* __restrict__ dt_sp,
    const float* __restrict__ cum, __hip_bfloat16* __restrict__ chunk_states) {
  __shared__ float sB[64][65];   // B[l][n]
  __shared__ float sW[64][65];   // x[l][p]*dt[l]*exp(cumL-cum[l])
  const int c = blockIdx.x, h = blockIdx.y, b = blockIdx.z;
  const int tid = threadIdx.x;
  const int bh = b * NHEADS + h;
  const float cumL = cum[(size_t)bh * TLEN + c * CHUNK + 63];
  for (int i = tid; i < 4096; i += 256) {
    const int l = i >> 6, j = i & 63;
    const size_t rowoff = ((size_t)(b * TLEN + c * CHUNK + l)) * CONVDIM;
    sB[l][j] = bf2f(convOut[rowoff + DINNER + j]);
    const float d = dt_sp[(size_t)bh * TLEN + c * CHUNK + l];
    const float dec = expf(cumL - cum[(size_t)bh * TLEN + c * CHUNK + l]);
    sW[l][j] = bf2f(convOut[rowoff + h * HEADDIM + j]) * d * dec;
  }
  __syncthreads();
  const int n = tid & 63, pg = tid >> 6;   // p = pg*16 + i
  float acc[16];
#pragma unroll
  for (int i = 0; i < 16; ++i) acc[i] = 0.f;
  for (int l = 0; l < 64; ++l) {
    const float bv = sB[l][n];
#pragma unroll
    for (int i = 0; i < 16; ++i) acc[i] += sW[l][pg * 16 + i] * bv;
  }
  const size_t outb = ((((size_t)b * NCHUNK + c) * NHEADS + h) * HEADDIM) * DSTATE;
#pragma unroll
  for (int i = 0; i < 16; ++i)
    chunk_states[outb + (size_t)(pg * 16 + i) * DSTATE + n] = f2bf(acc[i]);
}

// ---------------- inter-chunk scan, IN-PLACE: cs[c] <- state BEFORE chunk c ----------------
__global__ __launch_bounds__(256) void scan_kernel(
    __hip_bfloat16* __restrict__ cs, const float* __restrict__ cum) {
  const int idx = blockIdx.x * 256 + threadIdx.x;   // ((b*32+h)*64+p)*64+n
  const int n = idx & 63;
  int r = idx >> 6;
  const int p = r & 63; r >>= 6;
  const int h = r & 31;
  const int b = r >> 5;
  const int bh = b * NHEADS + h;
  const size_t stride_c = (size_t)NHEADS * HEADDIM * DSTATE;
  const size_t base = ((size_t)b * NCHUNK) * stride_c + ((size_t)h * HEADDIM + p) * DSTATE + n;
  float s = 0.f;
  for (int c = 0; c < NCHUNK; ++c) {
    const size_t off = base + (size_t)c * stride_c;
    const float val = bf2f(cs[off]);           // read chunk-state BEFORE overwrite
    cs[off] = f2bf(s);                         // write pre-state (exclusive scan)
    const float dec = expf(cum[(size_t)bh * TLEN + c * CHUNK + 63]);
    s = dec * s + val;
  }
}

// ---------------- per-chunk output: Yraw[b][t][h*64+p]  (bf16) ----------------
__global__ __launch_bounds__(256) void y_kernel(
    const __hip_bfloat16* __restrict__ convOut, const float* __restrict__ dt_sp,
    const float* __restrict__ cum, const __hip_bfloat16* __restrict__ states_pre,
    const float* __restrict__ Dparam, __hip_bfloat16* __restrict__ Yraw) {
  __shared__ __hip_bfloat16 sC[64][64];  // C[l][n]   (broadcast reads only)
  __shared__ float sX[64][64];           // x[s][p]*dt[s]
  __shared__ float sBSP[64][65];         // phase1: B[s][n]; phase2: SP[p][n]
  __shared__ float sG[64][64];           // G[l][s] then W[l][s]
  __shared__ float scum[64];
  const int c = blockIdx.x, h = blockIdx.y, b = blockIdx.z;
  const int tid = threadIdx.x;
  const int bh = b * NHEADS + h;
  const size_t tbase = (size_t)(b * TLEN + c * CHUNK);

  for (int i = tid; i < 4096; i += 256) {
    const int l = i >> 6, j = i & 63;
    const size_t rowoff = (tbase + l) * CONVDIM;
    sC[l][j] = convOut[rowoff + DINNER + DSTATE + j];
    sBSP[l][j] = bf2f(convOut[rowoff + DINNER + j]);
    sX[l][j] = bf2f(convOut[rowoff + h * HEADDIM + j]) * dt_sp[(size_t)bh * TLEN + c * CHUNK + l];
  }
  if (tid < 64) scum[tid] = cum[(size_t)bh * TLEN + c * CHUNK + tid];
  __syncthreads();

  // phase 1: G[l][s] = sum_n C[l][n] * B[s][n]
  {
    const int s = tid & 63, lg = tid >> 6;
    float accG[16];
#pragma unroll
    for (int i = 0; i < 16; ++i) accG[i] = 0.f;
    for (int n = 0; n < 64; ++n) {
      const float bv = sBSP[s][n];
#pragma unroll
      for (int i = 0; i < 16; ++i) accG[i] += bf2f(sC[lg * 16 + i][n]) * bv;
    }
#pragma unroll
    for (int i = 0; i < 16; ++i) sG[lg * 16 + i][s] = accG[i];
  }
  __syncthreads();

  // phase 2: W[l][s] = (s<=l) ? G*exp(cum[l]-cum[s]) : 0 ; reload sBSP <- SP[p][n]
  for (int e = tid; e < 4096; e += 256) {
    const int l = e >> 6, s = e & 63;
    const float v = sG[l][s];
    sG[l][s] = (s <= l) ? v * expf(scum[l] - scum[s]) : 0.f;
  }
  const size_t spbase = ((((size_t)b * NCHUNK + c) * NHEADS + h) * HEADDIM) * DSTATE;
  for (int i = tid; i < 4096; i += 256) {
    const int p = i >> 6, j = i & 63;
    sBSP[p][j] = bf2f(states_pre[spbase + (size_t)p * DSTATE + j]);
  }
  __syncthreads();

  // phase 3: Y[l][p] = sum_s W[l][s]*xdt[s][p] + exp(cum[l]) * sum_n C[l][n]*SP[p][n] + D*x
  const int p = tid & 63, lg = tid >> 6;
  float accD[16], accO[16];
#pragma unroll
  for (int i = 0; i < 16; ++i) { accD[i] = 0.f; accO[i] = 0.f; }
  for (int s = 0; s < 64; ++s) {
    const float xv = sX[s][p];
    const float spv = sBSP[p][s];
#pragma unroll
    for (int i = 0; i < 16; ++i) {
      const int l = lg * 16 + i;
      accD[i] += sG[l][s] * xv;
      accO[i] += bf2f(sC[l][s]) * spv;
    }
  }
  const float Dh = Dparam[h];
#pragma unroll
  for (int i = 0; i < 16; ++i) {
    const int l = lg * 16 + i;
    const size_t row = tbase + l;
    const float xval = bf2f(convOut[row * CONVDIM + h * HEADDIM + p]);
    Yraw[row * DINNER + h * HEADDIM + p] =
        f2bf(accD[i] + expf(scum[l]) * accO[i] + Dh * xval);
  }
}

// ---------------- gate (silu(z)) + RMSNorm -> bf16 ----------------
__global__ __launch_bounds__(256) void gate_norm_kernel(
    const __hip_bfloat16* __restrict__ Yraw, const __hip_bfloat16* __restrict__ z,
    const float* __restrict__ norm_w, __hip_bfloat16* __restrict__ ybf) {
  const int row = blockIdx.x;
  const int tid = threadIdx.x;
  const size_t base = (size_t)row * DINNER + tid * 8;
  float vals[8];
  float ss = 0.f;
#pragma unroll
  for (int j = 0; j < 8; ++j) {
    const float yv = bf2f(Yraw[base + j]);
    const float zv = bf2f(z[base + j]);
    const float g = zv / (1.f + expf(-zv));
    const float v = yv * g;
    vals[j] = v;
    ss += v * v;
  }
  __shared__ float red[256];
  red[tid] = ss;
  __syncthreads();
  for (int s = 128; s > 0; s >>= 1) {
    if (tid < s) red[tid] += red[tid + s];
    __syncthreads();
  }
  const float rms = rsqrtf(red[0] / (float)DINNER + 1e-5f);
#pragma unroll
  for (int j = 0; j < 8; ++j) {
    const float nw = norm_w[tid * 8 + j];
    ybf[base + j] = f2bf(vals[j] * rms * nw);
  }
}

// ---------------- launch ----------------
extern "C" void kernel_launch(void* const* d_in, const int* in_sizes, int n_in,
                              void* d_out, int out_size, void* d_ws, size_t ws_size,
                              hipStream_t stream) {
  const float* u       = (const float*)d_in[0];
  const float* W_in    = (const float*)d_in[1];
  const float* conv_w  = (const float*)d_in[2];
  const float* conv_b  = (const float*)d_in[3];
  const float* dt_bias = (const float*)d_in[4];
  const float* A_log   = (const float*)d_in[5];
  const float* Dp      = (const float*)d_in[6];
  const float* norm_w  = (const float*)d_in[7];
  const float* W_out   = (const float*)d_in[8];
  float* out = (float*)d_out;

  // --- workspace overlay (peak 148,176,896 bytes — identical to the R3-proven layout) ---
  char* w = (char*)d_ws;
  const size_t OFF_WB   = 0;                                     // Win_bf: 8,716,288
  const size_t OFF_Z    = OFF_WB  + (size_t)DPROJ * DMODEL * 2;  // z bf16: 33,554,432
  const size_t OFF_XBC  = OFF_Z   + (size_t)ROWS * DINNER * 2;   // xBC bf16: 35,651,584 (reused: Yraw)
  const size_t OFF_DTR  = OFF_XBC + (size_t)ROWS * CONVDIM * 2;  // dt_raw f32: 1,048,576
  const size_t OFF_CONV = OFF_DTR + (size_t)ROWS * NHEADS * 4;   // convOut bf16: 35,651,584
  const size_t OFF_CS   = OFF_CONV+ (size_t)ROWS * CONVDIM * 2;  // cs bf16: 33,554,432 (reused: ybf; u_bf lives here pre-step-4)
  // Win_bf region reused after gemm1: Wout_bf | dt_sp | cum
  const size_t OFF_WOB  = OFF_WB;
  const size_t OFF_DSP  = OFF_WB + (size_t)DMODEL * DINNER * 2;
  const size_t OFF_CUM  = OFF_DSP + (size_t)ROWS * NHEADS * 4;

  __hip_bfloat16* Win_bf  = (__hip_bfloat16*)(w + OFF_WB);
  __hip_bfloat16* Wout_bf = (__hip_bfloat16*)(w + OFF_WOB);
  __hip_bfloat16* Bz      = (__hip_bfloat16*)(w + OFF_Z);
  __hip_bfloat16* Bx      = (__hip_bfloat16*)(w + OFF_XBC);
  float*          Bd      = (float*)(w + OFF_DTR);
  __hip_bfloat16* Bconv   = (__hip_bfloat16*)(w + OFF_CONV);
  float*          dt_sp   = (float*)(w + OFF_DSP);
  float*          cum     = (float*)(w + OFF_CUM);
  __hip_bfloat16* Bcs     = (__hip_bfloat16*)(w + OFF_CS);
  __hip_bfloat16* u_bf    = (__hip_bfloat16*)(w + OFF_CS);  // dead before cs is written
  __hip_bfloat16* Yraw    = Bx;    // xBC_raw dead after conv
  __hip_bfloat16* ybf     = Bcs;   // states dead after y_kernel

  // 0. casts: W_in -> bf16, u -> bf16
  cast_f32_bf16<<<(DPROJ * DMODEL / 4 + 255) / 256, 256, 0, stream>>>(W_in, Win_bf, DPROJ * DMODEL);
  cast_f32_bf16<<<(ROWS * DMODEL / 4 + 255) / 256, 256, 0, stream>>>(u, u_bf, ROWS * DMODEL);
  // 1. in-projection (LDS-tiled MFMA), split epilogue: z | xBC_raw | dt_raw
  gemm_tiled<1><<<dim3(ROWS / 128, (DPROJ + 127) / 128), 256, 0, stream>>>(
      (const short*)u_bf, (const short*)Win_bf, Bz, Bx, Bd, nullptr, ROWS, DPROJ, DMODEL);
  // 0b. cast W_out -> bf16 (reuses Win_bf region, gemm1 done)
  cast_f32_bf16<<<(DMODEL * DINNER / 4 + 255) / 256, 256, 0, stream>>>(W_out, Wout_bf, DMODEL * DINNER);
  // 2. causal depthwise conv + SiLU
  conv_silu_kernel<<<(ROWS * CONVDIM) / 256, 256, 0, stream>>>(Bx, conv_w, conv_b, Bconv);
  // 3. dt softplus + per-chunk cumsum of A*dt
  dt_cumsum_kernel<<<(BSZ * NHEADS * NCHUNK + 255) / 256, 256, 0, stream>>>(
      Bd, dt_bias, A_log, dt_sp, cum);
  // 4. per-chunk states (bf16)
  chunk_state_kernel<<<dim3(NCHUNK, NHEADS, BSZ), 256, 0, stream>>>(Bconv, dt_sp, cum, Bcs);
  // 5. inter-chunk exclusive scan, in-place
  scan_kernel<<<(BSZ * NHEADS * HEADDIM * DSTATE) / 256, 256, 0, stream>>>(Bcs, cum);
  // 6. Y = diag + off + D*x  -> Yraw (bf16, into dead xBC_raw buffer)
  y_kernel<<<dim3(NCHUNK, NHEADS, BSZ), 256, 0, stream>>>(Bconv, dt_sp, cum, Bcs, Dp, Yraw);
  // 7. gate + RMSNorm -> ybf (into dead chunk-state buffer)
  gate_norm_kernel<<<ROWS, 256, 0, stream>>>(Yraw, Bz, norm_w, ybf);
  // 8. out-projection (LDS-tiled MFMA) -> f32 d_out
  gemm_tiled<0><<<dim3(ROWS / 128, DMODEL / 128), 256, 0, stream>>>(
      (const short*)ybf, (const short*)Wout_bf, nullptr, nullptr, nullptr, out, ROWS, DMODEL, DINNER);
}

// Round 5
// 494.347 us; speedup vs baseline: 2.1194x; 1.4640x over previous
//
#include <hip/hip_runtime.h>
#include <hip/hip_bf16.h>
#include <math.h>

// ---------------- constants ----------------
#define BSZ     2
#define TLEN    4096
#define DMODEL  1024
#define DINNER  2048
#define DSTATE  64
#define NHEADS  32
#define HEADDIM 64
#define CHUNK   64
#define NCHUNK  64            // TLEN / CHUNK
#define CONVDIM 2176          // DINNER + 2*DSTATE
#define DPROJ   4256          // 2*DINNER + 2*DSTATE + NHEADS
#define ROWS    8192          // BSZ*TLEN
#define LDP     72            // 64 + 8 pad (shorts) for MFMA LDS tiles

typedef __attribute__((ext_vector_type(8))) short s16x8;
typedef __attribute__((ext_vector_type(4))) float f32x4;

__device__ __forceinline__ float bf2f(__hip_bfloat16 x) { return __bfloat162float(x); }
__device__ __forceinline__ __hip_bfloat16 f2bf(float x) { return __float2bfloat16(x); }
__device__ __forceinline__ short f2bf_s(float x) {
  union { __hip_bfloat16 h; short s; } c; c.h = __float2bfloat16(x); return c.s;
}
__device__ __forceinline__ float s2f(short s) {
  union { unsigned int u; float f; } c; c.u = ((unsigned int)(unsigned short)s) << 16; return c.f;
}
__device__ __forceinline__ s16x8 scale8(s16x8 a, float s) {
  s16x8 r;
#pragma unroll
  for (int i = 0; i < 8; ++i) r[i] = f2bf_s(s2f(a[i]) * s);
  return r;
}

#define GLDS16(g, l)                                                        \
  __builtin_amdgcn_global_load_lds(                                         \
      (const __attribute__((address_space(1))) void*)(g),                   \
      (__attribute__((address_space(3))) void*)(l), 16, 0, 0)

// ---------------- f32 -> bf16 cast ----------------
__global__ __launch_bounds__(256) void cast_f32_bf16(
    const float* __restrict__ src, __hip_bfloat16* __restrict__ dst, int n) {
  const int i = (blockIdx.x * 256 + threadIdx.x) * 4;
  if (i + 3 < n) {
    const f32x4 v = *(const f32x4*)(src + i);
    dst[i + 0] = f2bf(v[0]); dst[i + 1] = f2bf(v[1]);
    dst[i + 2] = f2bf(v[2]); dst[i + 3] = f2bf(v[3]);
  } else {
    for (int j = i; j < n; ++j) dst[j] = f2bf(src[j]);
  }
}

// ---------------- LDS-tiled GEMM (m97 structure): C = A[M][K] @ B[N][K]^T ----------------
template <int SPLIT>
__global__ __launch_bounds__(256) void gemm_tiled(
    const short* __restrict__ A, const short* __restrict__ B,
    __hip_bfloat16* __restrict__ Cz, __hip_bfloat16* __restrict__ Cx,
    float* __restrict__ Cd, float* __restrict__ Cout, int M, int N, int K) {
  __shared__ short sA[128 * 32];   // [row][k] stride 32, NO padding (global_load_lds contract)
  __shared__ short sB[128 * 32];
  const int tid  = threadIdx.x;
  const int wave = tid >> 6, lane = tid & 63;
  const int lhi  = lane >> 4, llo = lane & 15;
  const int wm   = wave >> 1, wn = wave & 1;
  const int tm   = blockIdx.x * 128, tn = blockIdx.y * 128;

  const int srow  = lane >> 2;
  const int skcol = (lane & 3) * 8;

  f32x4 acc[4][4];
  const f32x4 fz = {0.f, 0.f, 0.f, 0.f};
#pragma unroll
  for (int mi = 0; mi < 4; ++mi)
#pragma unroll
    for (int ni = 0; ni < 4; ++ni) acc[mi][ni] = fz;

  for (int k0 = 0; k0 < K; k0 += 32) {
#pragma unroll
    for (int it = 0; it < 2; ++it) {
      const int seg = it * 4 + wave;
      const short* ga = A + (size_t)(tm + seg * 16 + srow) * K + k0 + skcol;
      GLDS16(ga, sA + seg * 512);
      const short* gb = B + (size_t)(tn + seg * 16 + srow) * K + k0 + skcol;
      GLDS16(gb, sB + seg * 512);
    }
    __syncthreads();
    s16x8 af[4], bfr[4];
#pragma unroll
    for (int i = 0; i < 4; ++i) {
      af[i]  = *(const s16x8*)(sA + (wm * 64 + i * 16 + llo) * 32 + lhi * 8);
      bfr[i] = *(const s16x8*)(sB + (wn * 64 + i * 16 + llo) * 32 + lhi * 8);
    }
#pragma unroll
    for (int mi = 0; mi < 4; ++mi)
#pragma unroll
      for (int ni = 0; ni < 4; ++ni)
        acc[mi][ni] = __builtin_amdgcn_mfma_f32_16x16x32_bf16(af[mi], bfr[ni], acc[mi][ni], 0, 0, 0);
    __syncthreads();
  }

#pragma unroll
  for (int mi = 0; mi < 4; ++mi)
#pragma unroll
    for (int ni = 0; ni < 4; ++ni)
#pragma unroll
      for (int r = 0; r < 4; ++r) {
        const int row = tm + wm * 64 + mi * 16 + lhi * 4 + r;
        const int col = tn + wn * 64 + ni * 16 + llo;
        if (col >= N) continue;
        const float v = acc[mi][ni][r];
        if (SPLIT) {
          if (col < DINNER)                Cz[(size_t)row * DINNER + col] = f2bf(v);
          else if (col < DINNER + CONVDIM) Cx[(size_t)row * CONVDIM + (col - DINNER)] = f2bf(v);
          else                             Cd[(size_t)row * NHEADS + (col - DINNER - CONVDIM)] = v;
        } else {
          Cout[(size_t)row * N + col] = v;
        }
      }
}

// ---------------- conv1d (depthwise, causal, width 4) + SiLU ----------------
__global__ __launch_bounds__(256) void conv_silu_kernel(
    const __hip_bfloat16* __restrict__ xBC, const float* __restrict__ conv_w,
    const float* __restrict__ conv_b, __hip_bfloat16* __restrict__ convOut) {
  const int idx = blockIdx.x * 256 + threadIdx.x;
  if (idx >= ROWS * CONVDIM) return;
  const int c  = idx % CONVDIM;
  const int bt = idx / CONVDIM;
  const int t  = bt & (TLEN - 1);
  const int b  = bt >> 12;
  float acc = conv_b[c];
#pragma unroll
  for (int k = 0; k < 4; ++k) {
    const int tt = t - 3 + k;
    if (tt >= 0)
      acc += conv_w[c * 4 + k] *
             bf2f(xBC[((size_t)(b * TLEN + tt)) * CONVDIM + c]);
  }
  const float s = acc / (1.f + expf(-acc));
  convOut[(size_t)bt * CONVDIM + c] = f2bf(s);
}

// ---------------- dt = softplus(dt_raw + bias); cum = per-chunk cumsum(A*dt) ----------------
__global__ __launch_bounds__(256) void dt_cumsum_kernel(
    const float* __restrict__ dt_raw, const float* __restrict__ dt_bias,
    const float* __restrict__ A_log, float* __restrict__ dt_sp, float* __restrict__ cum) {
  const int idx = blockIdx.x * 256 + threadIdx.x;
  if (idx >= BSZ * NHEADS * NCHUNK) return;
  const int c  = idx & 63;
  const int bh = idx >> 6;
  const int h  = bh & 31;
  const int b  = bh >> 5;
  const float bias = dt_bias[h];
  const float A = -expf(A_log[h]);
  float run = 0.f;
  for (int l = 0; l < CHUNK; ++l) {
    const int t = c * CHUNK + l;
    const float raw = dt_raw[((size_t)(b * TLEN + t)) * NHEADS + h] + bias;
    const float d = (raw > 20.f) ? raw : log1pf(expf(raw));
    run += A * d;
    dt_sp[(size_t)bh * TLEN + t] = d;
    cum[(size_t)bh * TLEN + t] = run;
  }
}

// ---------------- per-chunk state (MFMA): cs[p][n] = sum_l xd[l][p]*B[l][n] ----------------
// xd[l][p] = x[l][p]*dt[l]*exp(cumL-cum[l]).  a=xd^T rows p, b=B^T rows n, k=l.
__global__ __launch_bounds__(256) void chunk_state_kernel(
    const __hip_bfloat16* __restrict__ convOut, const float* __restrict__ dt_sp,
    const float* __restrict__ cum, __hip_bfloat16* __restrict__ chunk_states) {
  __shared__ short sBT [64 * LDP];   // B^T [n][l]
  __shared__ short sXdT[64 * LDP];   // xd^T [p][l]
  const int c = blockIdx.x, h = blockIdx.y, b = blockIdx.z;
  const int tid = threadIdx.x;
  const int wave = tid >> 6, lane = tid & 63;
  const int lhi = lane >> 4, llo = lane & 15;
  const int bh = b * NHEADS + h;
  const float cumL = cum[(size_t)bh * TLEN + c * CHUNK + 63];
  const short* cOut = (const short*)convOut;

  for (int v = tid; v < 512; v += 256) {
    const int l = v >> 3, ch = v & 7;
    const size_t rowoff = ((size_t)(b * TLEN + c * CHUNK + l)) * CONVDIM;
    const s16x8 bv = *(const s16x8*)(cOut + rowoff + DINNER + ch * 8);
    const float wgt = dt_sp[(size_t)bh * TLEN + c * CHUNK + l] *
                      expf(cumL - cum[(size_t)bh * TLEN + c * CHUNK + l]);
    const s16x8 xv = *(const s16x8*)(cOut + rowoff + h * HEADDIM + ch * 8);
#pragma unroll
    for (int jj = 0; jj < 8; ++jj) {
      sBT [(ch * 8 + jj) * LDP + l] = bv[jj];
      sXdT[(ch * 8 + jj) * LDP + l] = f2bf_s(s2f(xv[jj]) * wgt);
    }
  }
  __syncthreads();

  const f32x4 fz = {0.f, 0.f, 0.f, 0.f};
  const s16x8 a0 = *(const s16x8*)(sXdT + (16 * wave + llo) * LDP + lhi * 8);
  const s16x8 a1 = *(const s16x8*)(sXdT + (16 * wave + llo) * LDP + 32 + lhi * 8);
  const size_t outb = ((((size_t)b * NCHUNK + c) * NHEADS + h) * HEADDIM) * DSTATE;
#pragma unroll
  for (int j = 0; j < 4; ++j) {
    const s16x8 b0 = *(const s16x8*)(sBT + (16 * j + llo) * LDP + lhi * 8);
    const s16x8 b1 = *(const s16x8*)(sBT + (16 * j + llo) * LDP + 32 + lhi * 8);
    f32x4 acc = fz;
    acc = __builtin_amdgcn_mfma_f32_16x16x32_bf16(a0, b0, acc, 0, 0, 0);
    acc = __builtin_amdgcn_mfma_f32_16x16x32_bf16(a1, b1, acc, 0, 0, 0);
#pragma unroll
    for (int r = 0; r < 4; ++r) {
      const int p = 16 * wave + lhi * 4 + r;      // C/D: row=(lane>>4)*4+r
      const int n = 16 * j + llo;                 // col=lane&15
      chunk_states[outb + (size_t)p * DSTATE + n] = f2bf(acc[r]);
    }
  }
}

// ---------------- inter-chunk scan, IN-PLACE ----------------
__global__ __launch_bounds__(256) void scan_kernel(
    __hip_bfloat16* __restrict__ cs, const float* __restrict__ cum) {
  const int idx = blockIdx.x * 256 + threadIdx.x;
  const int n = idx & 63;
  int r = idx >> 6;
  const int p = r & 63; r >>= 6;
  const int h = r & 31;
  const int b = r >> 5;
  const int bh = b * NHEADS + h;
  const size_t stride_c = (size_t)NHEADS * HEADDIM * DSTATE;
  const size_t base = ((size_t)b * NCHUNK) * stride_c + ((size_t)h * HEADDIM + p) * DSTATE + n;
  float s = 0.f;
  for (int c = 0; c < NCHUNK; ++c) {
    const size_t off = base + (size_t)c * stride_c;
    const float val = bf2f(cs[off]);
    cs[off] = f2bf(s);
    const float dec = expf(cum[(size_t)bh * TLEN + c * CHUNK + 63]);
    s = dec * s + val;
  }
}

// ---------------- per-chunk output (MFMA) ----------------
// G = C.B^T (k=n); W = mask-decay(G) -> LDS bf16; Y = W.xdt^T + (e^cum * C).SP^T + D*x
__global__ __launch_bounds__(256) void y_kernel(
    const __hip_bfloat16* __restrict__ convOut, const float* __restrict__ dt_sp,
    const float* __restrict__ cum, const __hip_bfloat16* __restrict__ states_pre,
    const float* __restrict__ Dparam, __hip_bfloat16* __restrict__ Yraw) {
  __shared__ short sC [64 * LDP];   // C[l][n]
  __shared__ short sBW[64 * LDP];   // phase1: B[s][n]; phase3: W[l][s]
  __shared__ short sXT[64 * LDP];   // xdt^T [p][s]
  __shared__ short sSP[64 * LDP];   // SP[p][n]
  __shared__ float scum[64];
  const int c = blockIdx.x, h = blockIdx.y, b = blockIdx.z;
  const int tid = threadIdx.x;
  const int wave = tid >> 6, lane = tid & 63;
  const int lhi = lane >> 4, llo = lane & 15;
  const int bh = b * NHEADS + h;
  const size_t tbase = (size_t)(b * TLEN + c * CHUNK);
  const short* cOut = (const short*)convOut;
  const size_t spbase = ((((size_t)b * NCHUNK + c) * NHEADS + h) * HEADDIM) * DSTATE;
  const f32x4 fz = {0.f, 0.f, 0.f, 0.f};

  // ---- stage ----
  for (int v = tid; v < 512; v += 256) {
    const int r = v >> 3, ch = v & 7;
    const size_t rowoff = (tbase + r) * CONVDIM;
    *(s16x8*)(sC  + r * LDP + ch * 8) = *(const s16x8*)(cOut + rowoff + DINNER + DSTATE + ch * 8);
    *(s16x8*)(sBW + r * LDP + ch * 8) = *(const s16x8*)(cOut + rowoff + DINNER + ch * 8);
    *(s16x8*)(sSP + r * LDP + ch * 8) = *(const s16x8*)((const short*)states_pre + spbase + r * 64 + ch * 8);
    const float dt = dt_sp[(size_t)bh * TLEN + c * CHUNK + r];
    const s16x8 xv = *(const s16x8*)(cOut + rowoff + h * HEADDIM + ch * 8);
#pragma unroll
    for (int jj = 0; jj < 8; ++jj)
      sXT[(ch * 8 + jj) * LDP + r] = f2bf_s(s2f(xv[jj]) * dt);
  }
  if (tid < 64) scum[tid] = cum[(size_t)bh * TLEN + c * CHUNK + tid];
  __syncthreads();

  // ---- phase 1: G[l][s], wave handles l in [16w,16w+16) ----
  const s16x8 aC0 = *(const s16x8*)(sC + (16 * wave + llo) * LDP + lhi * 8);
  const s16x8 aC1 = *(const s16x8*)(sC + (16 * wave + llo) * LDP + 32 + lhi * 8);
  f32x4 g[4];
#pragma unroll
  for (int j = 0; j < 4; ++j) {
    const s16x8 b0 = *(const s16x8*)(sBW + (16 * j + llo) * LDP + lhi * 8);
    const s16x8 b1 = *(const s16x8*)(sBW + (16 * j + llo) * LDP + 32 + lhi * 8);
    f32x4 acc = fz;
    acc = __builtin_amdgcn_mfma_f32_16x16x32_bf16(aC0, b0, acc, 0, 0, 0);
    acc = __builtin_amdgcn_mfma_f32_16x16x32_bf16(aC1, b1, acc, 0, 0, 0);
    g[j] = acc;
  }
  __syncthreads();   // all waves done reading sBW

  // ---- phase 2: mask+decay, write W (bf16) into sBW as [l][s] ----
  float cl[4];
#pragma unroll
  for (int r = 0; r < 4; ++r) cl[r] = scum[16 * wave + lhi * 4 + r];
#pragma unroll
  for (int j = 0; j < 4; ++j) {
    const int s = 16 * j + llo;
    const float cs_ = scum[s];
#pragma unroll
    for (int r = 0; r < 4; ++r) {
      const int l = 16 * wave + lhi * 4 + r;
      const float v = (s <= l) ? g[j][r] * expf(cl[r] - cs_) : 0.f;
      sBW[l * LDP + s] = f2bf_s(v);
    }
  }
  __syncthreads();

  // ---- phase 3: Y[l][p] ----
  const float el = expf(scum[16 * wave + llo]);     // row l = 16w+llo of A-frags
  const s16x8 aCs0 = scale8(aC0, el);
  const s16x8 aCs1 = scale8(aC1, el);
  const s16x8 aW0 = *(const s16x8*)(sBW + (16 * wave + llo) * LDP + lhi * 8);
  const s16x8 aW1 = *(const s16x8*)(sBW + (16 * wave + llo) * LDP + 32 + lhi * 8);
  const float Dh = Dparam[h];
#pragma unroll
  for (int j = 0; j < 4; ++j) {
    const s16x8 bx0 = *(const s16x8*)(sXT + (16 * j + llo) * LDP + lhi * 8);
    const s16x8 bx1 = *(const s16x8*)(sXT + (16 * j + llo) * LDP + 32 + lhi * 8);
    const s16x8 bs0 = *(const s16x8*)(sSP + (16 * j + llo) * LDP + lhi * 8);
    const s16x8 bs1 = *(const s16x8*)(sSP + (16 * j + llo) * LDP + 32 + lhi * 8);
    f32x4 acc = fz;
    acc = __builtin_amdgcn_mfma_f32_16x16x32_bf16(aW0, bx0, acc, 0, 0, 0);
    acc = __builtin_amdgcn_mfma_f32_16x16x32_bf16(aW1, bx1, acc, 0, 0, 0);
    acc = __builtin_amdgcn_mfma_f32_16x16x32_bf16(aCs0, bs0, acc, 0, 0, 0);
    acc = __builtin_amdgcn_mfma_f32_16x16x32_bf16(aCs1, bs1, acc, 0, 0, 0);
#pragma unroll
    for (int r = 0; r < 4; ++r) {
      const int l = 16 * wave + lhi * 4 + r;
      const int p = 16 * j + llo;
      const size_t row = tbase + l;
      const float xval = bf2f(convOut[row * CONVDIM + h * HEADDIM + p]);
      Yraw[row * DINNER + h * HEADDIM + p] = f2bf(acc[r] + Dh * xval);
    }
  }
}

// ---------------- gate (silu(z)) + RMSNorm -> bf16 ----------------
__global__ __launch_bounds__(256) void gate_norm_kernel(
    const __hip_bfloat16* __restrict__ Yraw, const __hip_bfloat16* __restrict__ z,
    const float* __restrict__ norm_w, __hip_bfloat16* __restrict__ ybf) {
  const int row = blockIdx.x;
  const int tid = threadIdx.x;
  const size_t base = (size_t)row * DINNER + tid * 8;
  float vals[8];
  float ss = 0.f;
#pragma unroll
  for (int j = 0; j < 8; ++j) {
    const float yv = bf2f(Yraw[base + j]);
    const float zv = bf2f(z[base + j]);
    const float g = zv / (1.f + expf(-zv));
    const float v = yv * g;
    vals[j] = v;
    ss += v * v;
  }
  __shared__ float red[256];
  red[tid] = ss;
  __syncthreads();
  for (int s = 128; s > 0; s >>= 1) {
    if (tid < s) red[tid] += red[tid + s];
    __syncthreads();
  }
  const float rms = rsqrtf(red[0] / (float)DINNER + 1e-5f);
#pragma unroll
  for (int j = 0; j < 8; ++j) {
    const float nw = norm_w[tid * 8 + j];
    ybf[base + j] = f2bf(vals[j] * rms * nw);
  }
}

// ---------------- launch ----------------
extern "C" void kernel_launch(void* const* d_in, const int* in_sizes, int n_in,
                              void* d_out, int out_size, void* d_ws, size_t ws_size,
                              hipStream_t stream) {
  const float* u       = (const float*)d_in[0];
  const float* W_in    = (const float*)d_in[1];
  const float* conv_w  = (const float*)d_in[2];
  const float* conv_b  = (const float*)d_in[3];
  const float* dt_bias = (const float*)d_in[4];
  const float* A_log   = (const float*)d_in[5];
  const float* Dp      = (const float*)d_in[6];
  const float* norm_w  = (const float*)d_in[7];
  const float* W_out   = (const float*)d_in[8];
  float* out = (float*)d_out;

  // --- workspace overlay (peak 148,176,896 bytes — proven layout) ---
  char* w = (char*)d_ws;
  const size_t OFF_WB   = 0;
  const size_t OFF_Z    = OFF_WB  + (size_t)DPROJ * DMODEL * 2;
  const size_t OFF_XBC  = OFF_Z   + (size_t)ROWS * DINNER * 2;
  const size_t OFF_DTR  = OFF_XBC + (size_t)ROWS * CONVDIM * 2;
  const size_t OFF_CONV = OFF_DTR + (size_t)ROWS * NHEADS * 4;
  const size_t OFF_CS   = OFF_CONV+ (size_t)ROWS * CONVDIM * 2;
  const size_t OFF_WOB  = OFF_WB;
  const size_t OFF_DSP  = OFF_WB + (size_t)DMODEL * DINNER * 2;
  const size_t OFF_CUM  = OFF_DSP + (size_t)ROWS * NHEADS * 4;

  __hip_bfloat16* Win_bf  = (__hip_bfloat16*)(w + OFF_WB);
  __hip_bfloat16* Wout_bf = (__hip_bfloat16*)(w + OFF_WOB);
  __hip_bfloat16* Bz      = (__hip_bfloat16*)(w + OFF_Z);
  __hip_bfloat16* Bx      = (__hip_bfloat16*)(w + OFF_XBC);
  float*          Bd      = (float*)(w + OFF_DTR);
  __hip_bfloat16* Bconv   = (__hip_bfloat16*)(w + OFF_CONV);
  float*          dt_sp   = (float*)(w + OFF_DSP);
  float*          cum     = (float*)(w + OFF_CUM);
  __hip_bfloat16* Bcs     = (__hip_bfloat16*)(w + OFF_CS);
  __hip_bfloat16* u_bf    = (__hip_bfloat16*)(w + OFF_CS);
  __hip_bfloat16* Yraw    = Bx;
  __hip_bfloat16* ybf     = Bcs;

  cast_f32_bf16<<<(DPROJ * DMODEL / 4 + 255) / 256, 256, 0, stream>>>(W_in, Win_bf, DPROJ * DMODEL);
  cast_f32_bf16<<<(ROWS * DMODEL / 4 + 255) / 256, 256, 0, stream>>>(u, u_bf, ROWS * DMODEL);
  gemm_tiled<1><<<dim3(ROWS / 128, (DPROJ + 127) / 128), 256, 0, stream>>>(
      (const short*)u_bf, (const short*)Win_bf, Bz, Bx, Bd, nullptr, ROWS, DPROJ, DMODEL);
  cast_f32_bf16<<<(DMODEL * DINNER / 4 + 255) / 256, 256, 0, stream>>>(W_out, Wout_bf, DMODEL * DINNER);
  conv_silu_kernel<<<(ROWS * CONVDIM) / 256, 256, 0, stream>>>(Bx, conv_w, conv_b, Bconv);
  dt_cumsum_kernel<<<(BSZ * NHEADS * NCHUNK + 255) / 256, 256, 0, stream>>>(
      Bd, dt_bias, A_log, dt_sp, cum);
  chunk_state_kernel<<<dim3(NCHUNK, NHEADS, BSZ), 256, 0, stream>>>(Bconv, dt_sp, cum, Bcs);
  scan_kernel<<<(BSZ * NHEADS * HEADDIM * DSTATE) / 256, 256, 0, stream>>>(Bcs, cum);
  y_kernel<<<dim3(NCHUNK, NHEADS, BSZ), 256, 0, stream>>>(Bconv, dt_sp, cum, Bcs, Dp, Yraw);
  gate_norm_kernel<<<ROWS, 256, 0, stream>>>(Yraw, Bz, norm_w, ybf);
  gemm_tiled<0><<<dim3(ROWS / 128, DMODEL / 128), 256, 0, stream>>>(
      (const short*)ybf, (const short*)Wout_bf, nullptr, nullptr, nullptr, out, ROWS, DMODEL, DINNER);
}

// Round 6
// 398.379 us; speedup vs baseline: 2.6300x; 1.2409x over previous
//
#include <hip/hip_runtime.h>
#include <hip/hip_bf16.h>
#include <math.h>

// ---------------- constants ----------------
#define BSZ     2
#define TLEN    4096
#define DMODEL  1024
#define DINNER  2048
#define DSTATE  64
#define NHEADS  32
#define HEADDIM 64
#define CHUNK   64
#define NCHUNK  64            // TLEN / CHUNK
#define CONVDIM 2176          // DINNER + 2*DSTATE
#define DPROJ   4256          // 2*DINNER + 2*DSTATE + NHEADS
#define ROWS    8192          // BSZ*TLEN
#define LDP     72            // 64 + 8 pad (shorts) for MFMA LDS tiles

typedef __attribute__((ext_vector_type(8))) short s16x8;
typedef __attribute__((ext_vector_type(4))) float f32x4;

__device__ __forceinline__ float bf2f(__hip_bfloat16 x) { return __bfloat162float(x); }
__device__ __forceinline__ __hip_bfloat16 f2bf(float x) { return __float2bfloat16(x); }
__device__ __forceinline__ short f2bf_s(float x) {
  union { __hip_bfloat16 h; short s; } c; c.h = __float2bfloat16(x); return c.s;
}
__device__ __forceinline__ float s2f(short s) {
  union { unsigned int u; float f; } c; c.u = ((unsigned int)(unsigned short)s) << 16; return c.f;
}
__device__ __forceinline__ s16x8 scale8(s16x8 a, float s) {
  s16x8 r;
#pragma unroll
  for (int i = 0; i < 8; ++i) r[i] = f2bf_s(s2f(a[i]) * s);
  return r;
}

#define GLDS16(g, l)                                                        \
  __builtin_amdgcn_global_load_lds(                                         \
      (const __attribute__((address_space(1))) void*)(g),                   \
      (__attribute__((address_space(3))) void*)(l), 16, 0, 0)

// ---------------- f32 -> bf16 casts ----------------
__global__ __launch_bounds__(256) void cast_f32_bf16(
    const float* __restrict__ src, __hip_bfloat16* __restrict__ dst, int n) {
  const int i = (blockIdx.x * 256 + threadIdx.x) * 4;
  if (i + 3 < n) {
    const f32x4 v = *(const f32x4*)(src + i);
    dst[i + 0] = f2bf(v[0]); dst[i + 1] = f2bf(v[1]);
    dst[i + 2] = f2bf(v[2]); dst[i + 3] = f2bf(v[3]);
  } else {
    for (int j = i; j < n; ++j) dst[j] = f2bf(src[j]);
  }
}

__global__ __launch_bounds__(256) void cast2_f32_bf16(
    const float* __restrict__ s1, __hip_bfloat16* __restrict__ d1, int n1,
    const float* __restrict__ s2, __hip_bfloat16* __restrict__ d2, int n2) {
  const int i = (blockIdx.x * 256 + threadIdx.x) * 4;   // n1, n2 divisible by 4
  if (i < n1) {
    const f32x4 v = *(const f32x4*)(s1 + i);
    d1[i + 0] = f2bf(v[0]); d1[i + 1] = f2bf(v[1]);
    d1[i + 2] = f2bf(v[2]); d1[i + 3] = f2bf(v[3]);
  } else {
    const int j = i - n1;
    if (j < n2) {
      const f32x4 v = *(const f32x4*)(s2 + j);
      d2[j + 0] = f2bf(v[0]); d2[j + 1] = f2bf(v[1]);
      d2[j + 2] = f2bf(v[2]); d2[j + 3] = f2bf(v[3]);
    }
  }
}

// ---------------- LDS-tiled GEMM, BK=64, XOR-swizzled: C = A[M][K] @ B[N][K]^T ----------------
// 128x128 tile, 4 waves each 64x64. Tile row = 64 shorts (128 B) = 8 chunks of 16 B.
// Chunk c of row r is stored at LDS slot (c ^ (r&7)) — applied at stage time via the
// global address (wave-uniform GLDS dest + lane*16B contract preserved; each 8-lane
// group still covers one contiguous 128 B global row). ds_read applies the same XOR,
// so every wave b128 read spreads uniformly over all 8 bank groups (2-way = free).
template <int SPLIT>
__global__ __launch_bounds__(256) void gemm_tiled(
    const short* __restrict__ A, const short* __restrict__ B,
    __hip_bfloat16* __restrict__ Cz, __hip_bfloat16* __restrict__ Cx,
    float* __restrict__ Cd, float* __restrict__ Cout, int M, int N, int K) {
  __shared__ __align__(16) short sA[128 * 64];   // 16 KB
  __shared__ __align__(16) short sB[128 * 64];   // 16 KB
  const int tid  = threadIdx.x;
  const int wave = tid >> 6, lane = tid & 63;
  const int lhi  = lane >> 4, llo = lane & 15;
  const int wm   = wave >> 1, wn = wave & 1;
  const int tm   = blockIdx.x * 128, tn = blockIdx.y * 128;

  // staging map: seg covers 8 rows (1 KB); lane i -> row seg*8 + i/8, global chunk (i&7)^(i>>3)
  const int srow = lane >> 3;                 // 0..7
  const int skc  = ((lane & 7) ^ srow) * 8;   // swizzled k-chunk (shorts)

  f32x4 acc[4][4];
  const f32x4 fz = {0.f, 0.f, 0.f, 0.f};
#pragma unroll
  for (int mi = 0; mi < 4; ++mi)
#pragma unroll
    for (int ni = 0; ni < 4; ++ni) acc[mi][ni] = fz;

  for (int k0 = 0; k0 < K; k0 += 64) {
#pragma unroll
    for (int t = 0; t < 4; ++t) {
      const int seg = t * 4 + wave;                      // 0..15
      const int rl  = seg * 8 + srow;
      GLDS16(A + (size_t)(tm + rl) * K + k0 + skc, sA + seg * 512);
      GLDS16(B + (size_t)(tn + rl) * K + k0 + skc, sB + seg * 512);
    }
    __syncthreads();
#pragma unroll
    for (int sub = 0; sub < 2; ++sub) {
      s16x8 af[4], bfr[4];
#pragma unroll
      for (int i = 0; i < 4; ++i) {
        const int am = wm * 64 + i * 16 + llo;
        af[i]  = *(const s16x8*)(sA + am * 64 + ((sub * 4 + lhi) ^ (am & 7)) * 8);
        const int bn = wn * 64 + i * 16 + llo;
        bfr[i] = *(const s16x8*)(sB + bn * 64 + ((sub * 4 + lhi) ^ (bn & 7)) * 8);
      }
#pragma unroll
      for (int mi = 0; mi < 4; ++mi)
#pragma unroll
        for (int ni = 0; ni < 4; ++ni)
          acc[mi][ni] = __builtin_amdgcn_mfma_f32_16x16x32_bf16(af[mi], bfr[ni], acc[mi][ni], 0, 0, 0);
    }
    __syncthreads();
  }

#pragma unroll
  for (int mi = 0; mi < 4; ++mi)
#pragma unroll
    for (int ni = 0; ni < 4; ++ni)
#pragma unroll
      for (int r = 0; r < 4; ++r) {
        const int row = tm + wm * 64 + mi * 16 + lhi * 4 + r;
        const int col = tn + wn * 64 + ni * 16 + llo;
        if (col >= N) continue;
        const float v = acc[mi][ni][r];
        if (SPLIT) {
          if (col < DINNER)                Cz[(size_t)row * DINNER + col] = f2bf(v);
          else if (col < DINNER + CONVDIM) Cx[(size_t)row * CONVDIM + (col - DINNER)] = f2bf(v);
          else                             Cd[(size_t)row * NHEADS + (col - DINNER - CONVDIM)] = v;
        } else {
          Cout[(size_t)row * N + col] = v;
        }
      }
}

// ---------------- conv1d (depthwise, causal, width 4) + SiLU — vectorized 8 ch/thread ----------------
__global__ __launch_bounds__(256) void conv_silu_kernel(
    const __hip_bfloat16* __restrict__ xBC, const float* __restrict__ conv_w,
    const float* __restrict__ conv_b, __hip_bfloat16* __restrict__ convOut) {
  const int idx8 = blockIdx.x * 256 + threadIdx.x;   // bt*272 + c8
  const int c8 = idx8 % 272;
  const int bt = idx8 / 272;
  if (bt >= ROWS) return;
  const int t = bt & (TLEN - 1);
  const int c = c8 * 8;
  const short* xp = (const short*)xBC;

  f32x4 w4[8];
#pragma unroll
  for (int j = 0; j < 8; ++j) w4[j] = *(const f32x4*)(conv_w + (c + j) * 4);

  float acc[8];
  const f32x4 b0 = *(const f32x4*)(conv_b + c);
  const f32x4 b1 = *(const f32x4*)(conv_b + c + 4);
#pragma unroll
  for (int j = 0; j < 4; ++j) { acc[j] = b0[j]; acc[4 + j] = b1[j]; }

#pragma unroll
  for (int k = 0; k < 4; ++k) {
    const int tt = t - 3 + k;
    if (tt < 0) continue;
    const s16x8 xv = *(const s16x8*)(xp + (size_t)(bt - 3 + k) * CONVDIM + c);
#pragma unroll
    for (int j = 0; j < 8; ++j) acc[j] += w4[j][k] * s2f(xv[j]);
  }
  s16x8 o;
#pragma unroll
  for (int j = 0; j < 8; ++j) {
    const float s = acc[j] / (1.f + expf(-acc[j]));
    o[j] = f2bf_s(s);
  }
  *(s16x8*)((short*)convOut + (size_t)bt * CONVDIM + c) = o;
}

// ---------------- dt softplus + per-chunk cumsum of A*dt — one wave per (b,h,chunk) ----------------
__global__ __launch_bounds__(256) void dt_cumsum_kernel(
    const float* __restrict__ dt_raw, const float* __restrict__ dt_bias,
    const float* __restrict__ A_log, float* __restrict__ dt_sp, float* __restrict__ cum) {
  const int lane = threadIdx.x & 63;
  const int w = blockIdx.x * 4 + (threadIdx.x >> 6);   // bh*64 + c
  const int c = w & 63, bh = w >> 6;
  const int h = bh & 31, b = bh >> 5;
  const int t = c * CHUNK + lane;
  const float raw = dt_raw[((size_t)(b * TLEN + t)) * NHEADS + h] + dt_bias[h];
  const float d = (raw > 20.f) ? raw : log1pf(expf(raw));
  float v = -expf(A_log[h]) * d;
#pragma unroll
  for (int off = 1; off < 64; off <<= 1) {
    const float nb = __shfl_up(v, off, 64);
    if (lane >= off) v += nb;
  }
  dt_sp[(size_t)bh * TLEN + t] = d;
  cum[(size_t)bh * TLEN + t] = v;
}

// ---------------- per-chunk state (MFMA): cs[p][n] = sum_l xd[l][p]*B[l][n] ----------------
__global__ __launch_bounds__(256) void chunk_state_kernel(
    const __hip_bfloat16* __restrict__ convOut, const float* __restrict__ dt_sp,
    const float* __restrict__ cum, __hip_bfloat16* __restrict__ chunk_states) {
  __shared__ __align__(16) short sBT [64 * LDP];   // B^T [n][l]
  __shared__ __align__(16) short sXdT[64 * LDP];   // xd^T [p][l]
  const int c = blockIdx.x, h = blockIdx.y, b = blockIdx.z;
  const int tid = threadIdx.x;
  const int wave = tid >> 6, lane = tid & 63;
  const int lhi = lane >> 4, llo = lane & 15;
  const int bh = b * NHEADS + h;
  const float cumL = cum[(size_t)bh * TLEN + c * CHUNK + 63];
  const short* cOut = (const short*)convOut;

  for (int v = tid; v < 512; v += 256) {
    const int l = v >> 3, ch = v & 7;
    const size_t rowoff = ((size_t)(b * TLEN + c * CHUNK + l)) * CONVDIM;
    const s16x8 bv = *(const s16x8*)(cOut + rowoff + DINNER + ch * 8);
    const float wgt = dt_sp[(size_t)bh * TLEN + c * CHUNK + l] *
                      expf(cumL - cum[(size_t)bh * TLEN + c * CHUNK + l]);
    const s16x8 xv = *(const s16x8*)(cOut + rowoff + h * HEADDIM + ch * 8);
#pragma unroll
    for (int jj = 0; jj < 8; ++jj) {
      sBT [(ch * 8 + jj) * LDP + l] = bv[jj];
      sXdT[(ch * 8 + jj) * LDP + l] = f2bf_s(s2f(xv[jj]) * wgt);
    }
  }
  __syncthreads();

  const f32x4 fz = {0.f, 0.f, 0.f, 0.f};
  const s16x8 a0 = *(const s16x8*)(sXdT + (16 * wave + llo) * LDP + lhi * 8);
  const s16x8 a1 = *(const s16x8*)(sXdT + (16 * wave + llo) * LDP + 32 + lhi * 8);
  const size_t outb = ((((size_t)b * NCHUNK + c) * NHEADS + h) * HEADDIM) * DSTATE;
#pragma unroll
  for (int j = 0; j < 4; ++j) {
    const s16x8 b0 = *(const s16x8*)(sBT + (16 * j + llo) * LDP + lhi * 8);
    const s16x8 b1 = *(const s16x8*)(sBT + (16 * j + llo) * LDP + 32 + lhi * 8);
    f32x4 acc = fz;
    acc = __builtin_amdgcn_mfma_f32_16x16x32_bf16(a0, b0, acc, 0, 0, 0);
    acc = __builtin_amdgcn_mfma_f32_16x16x32_bf16(a1, b1, acc, 0, 0, 0);
#pragma unroll
    for (int r = 0; r < 4; ++r) {
      const int p = 16 * wave + lhi * 4 + r;
      const int n = 16 * j + llo;
      chunk_states[outb + (size_t)p * DSTATE + n] = f2bf(acc[r]);
    }
  }
}

// ---------------- inter-chunk scan, IN-PLACE ----------------
__global__ __launch_bounds__(256) void scan_kernel(
    __hip_bfloat16* __restrict__ cs, const float* __restrict__ cum) {
  const int idx = blockIdx.x * 256 + threadIdx.x;
  const int n = idx & 63;
  int r = idx >> 6;
  const int p = r & 63; r >>= 6;
  const int h = r & 31;
  const int b = r >> 5;
  const int bh = b * NHEADS + h;
  const size_t stride_c = (size_t)NHEADS * HEADDIM * DSTATE;
  const size_t base = ((size_t)b * NCHUNK) * stride_c + ((size_t)h * HEADDIM + p) * DSTATE + n;
  float s = 0.f;
  for (int c = 0; c < NCHUNK; ++c) {
    const size_t off = base + (size_t)c * stride_c;
    const float val = bf2f(cs[off]);
    cs[off] = f2bf(s);
    const float dec = expf(cum[(size_t)bh * TLEN + c * CHUNK + 63]);
    s = dec * s + val;
  }
}

// ---------------- per-chunk output (MFMA) ----------------
__global__ __launch_bounds__(256) void y_kernel(
    const __hip_bfloat16* __restrict__ convOut, const float* __restrict__ dt_sp,
    const float* __restrict__ cum, const __hip_bfloat16* __restrict__ states_pre,
    const float* __restrict__ Dparam, __hip_bfloat16* __restrict__ Yraw) {
  __shared__ __align__(16) short sC [64 * LDP];   // C[l][n]
  __shared__ __align__(16) short sBW[64 * LDP];   // phase1: B[s][n]; phase3: W[l][s]
  __shared__ __align__(16) short sXT[64 * LDP];   // xdt^T [p][s]
  __shared__ __align__(16) short sSP[64 * LDP];   // SP[p][n]
  __shared__ float scum[64];
  const int c = blockIdx.x, h = blockIdx.y, b = blockIdx.z;
  const int tid = threadIdx.x;
  const int wave = tid >> 6, lane = tid & 63;
  const int lhi = lane >> 4, llo = lane & 15;
  const int bh = b * NHEADS + h;
  const size_t tbase = (size_t)(b * TLEN + c * CHUNK);
  const short* cOut = (const short*)convOut;
  const size_t spbase = ((((size_t)b * NCHUNK + c) * NHEADS + h) * HEADDIM) * DSTATE;
  const f32x4 fz = {0.f, 0.f, 0.f, 0.f};

  for (int v = tid; v < 512; v += 256) {
    const int r = v >> 3, ch = v & 7;
    const size_t rowoff = (tbase + r) * CONVDIM;
    *(s16x8*)(sC  + r * LDP + ch * 8) = *(const s16x8*)(cOut + rowoff + DINNER + DSTATE + ch * 8);
    *(s16x8*)(sBW + r * LDP + ch * 8) = *(const s16x8*)(cOut + rowoff + DINNER + ch * 8);
    *(s16x8*)(sSP + r * LDP + ch * 8) = *(const s16x8*)((const short*)states_pre + spbase + r * 64 + ch * 8);
    const float dt = dt_sp[(size_t)bh * TLEN + c * CHUNK + r];
    const s16x8 xv = *(const s16x8*)(cOut + rowoff + h * HEADDIM + ch * 8);
#pragma unroll
    for (int jj = 0; jj < 8; ++jj)
      sXT[(ch * 8 + jj) * LDP + r] = f2bf_s(s2f(xv[jj]) * dt);
  }
  if (tid < 64) scum[tid] = cum[(size_t)bh * TLEN + c * CHUNK + tid];
  __syncthreads();

  // phase 1: G[l][s]
  const s16x8 aC0 = *(const s16x8*)(sC + (16 * wave + llo) * LDP + lhi * 8);
  const s16x8 aC1 = *(const s16x8*)(sC + (16 * wave + llo) * LDP + 32 + lhi * 8);
  f32x4 g[4];
#pragma unroll
  for (int j = 0; j < 4; ++j) {
    const s16x8 b0 = *(const s16x8*)(sBW + (16 * j + llo) * LDP + lhi * 8);
    const s16x8 b1 = *(const s16x8*)(sBW + (16 * j + llo) * LDP + 32 + lhi * 8);
    f32x4 acc = fz;
    acc = __builtin_amdgcn_mfma_f32_16x16x32_bf16(aC0, b0, acc, 0, 0, 0);
    acc = __builtin_amdgcn_mfma_f32_16x16x32_bf16(aC1, b1, acc, 0, 0, 0);
    g[j] = acc;
  }
  __syncthreads();

  // phase 2: W[l][s] = (s<=l) ? G*exp(cum[l]-cum[s]) : 0
  float cl[4];
#pragma unroll
  for (int r = 0; r < 4; ++r) cl[r] = scum[16 * wave + lhi * 4 + r];
#pragma unroll
  for (int j = 0; j < 4; ++j) {
    const int s = 16 * j + llo;
    const float cs_ = scum[s];
#pragma unroll
    for (int r = 0; r < 4; ++r) {
      const int l = 16 * wave + lhi * 4 + r;
      const float v = (s <= l) ? g[j][r] * expf(cl[r] - cs_) : 0.f;
      sBW[l * LDP + s] = f2bf_s(v);
    }
  }
  __syncthreads();

  // phase 3: Y[l][p]
  const float el = expf(scum[16 * wave + llo]);
  const s16x8 aCs0 = scale8(aC0, el);
  const s16x8 aCs1 = scale8(aC1, el);
  const s16x8 aW0 = *(const s16x8*)(sBW + (16 * wave + llo) * LDP + lhi * 8);
  const s16x8 aW1 = *(const s16x8*)(sBW + (16 * wave + llo) * LDP + 32 + lhi * 8);
  const float Dh = Dparam[h];
#pragma unroll
  for (int j = 0; j < 4; ++j) {
    const s16x8 bx0 = *(const s16x8*)(sXT + (16 * j + llo) * LDP + lhi * 8);
    const s16x8 bx1 = *(const s16x8*)(sXT + (16 * j + llo) * LDP + 32 + lhi * 8);
    const s16x8 bs0 = *(const s16x8*)(sSP + (16 * j + llo) * LDP + lhi * 8);
    const s16x8 bs1 = *(const s16x8*)(sSP + (16 * j + llo) * LDP + 32 + lhi * 8);
    f32x4 acc = fz;
    acc = __builtin_amdgcn_mfma_f32_16x16x32_bf16(aW0, bx0, acc, 0, 0, 0);
    acc = __builtin_amdgcn_mfma_f32_16x16x32_bf16(aW1, bx1, acc, 0, 0, 0);
    acc = __builtin_amdgcn_mfma_f32_16x16x32_bf16(aCs0, bs0, acc, 0, 0, 0);
    acc = __builtin_amdgcn_mfma_f32_16x16x32_bf16(aCs1, bs1, acc, 0, 0, 0);
#pragma unroll
    for (int r = 0; r < 4; ++r) {
      const int l = 16 * wave + lhi * 4 + r;
      const int p = 16 * j + llo;
      const size_t row = tbase + l;
      const float xval = bf2f(convOut[row * CONVDIM + h * HEADDIM + p]);
      Yraw[row * DINNER + h * HEADDIM + p] = f2bf(acc[r] + Dh * xval);
    }
  }
}

// ---------------- gate (silu(z)) + RMSNorm -> bf16 ----------------
__global__ __launch_bounds__(256) void gate_norm_kernel(
    const __hip_bfloat16* __restrict__ Yraw, const __hip_bfloat16* __restrict__ z,
    const float* __restrict__ norm_w, __hip_bfloat16* __restrict__ ybf) {
  const int row = blockIdx.x;
  const int tid = threadIdx.x;
  const size_t base = (size_t)row * DINNER + tid * 8;
  const s16x8 yv8 = *(const s16x8*)((const short*)Yraw + base);
  const s16x8 zv8 = *(const s16x8*)((const short*)z + base);
  float vals[8];
  float ss = 0.f;
#pragma unroll
  for (int j = 0; j < 8; ++j) {
    const float zv = s2f(zv8[j]);
    const float v = s2f(yv8[j]) * (zv / (1.f + expf(-zv)));
    vals[j] = v;
    ss += v * v;
  }
#pragma unroll
  for (int off = 32; off > 0; off >>= 1) ss += __shfl_down(ss, off, 64);
  __shared__ float red[4];
  if ((tid & 63) == 0) red[tid >> 6] = ss;
  __syncthreads();
  const float rms = rsqrtf((red[0] + red[1] + red[2] + red[3]) / (float)DINNER + 1e-5f);
  const f32x4 nw0 = *(const f32x4*)(norm_w + tid * 8);
  const f32x4 nw1 = *(const f32x4*)(norm_w + tid * 8 + 4);
  s16x8 o;
#pragma unroll
  for (int j = 0; j < 4; ++j) {
    o[j]     = f2bf_s(vals[j] * rms * nw0[j]);
    o[4 + j] = f2bf_s(vals[4 + j] * rms * nw1[j]);
  }
  *(s16x8*)((short*)ybf + base) = o;
}

// ---------------- launch ----------------
extern "C" void kernel_launch(void* const* d_in, const int* in_sizes, int n_in,
                              void* d_out, int out_size, void* d_ws, size_t ws_size,
                              hipStream_t stream) {
  const float* u       = (const float*)d_in[0];
  const float* W_in    = (const float*)d_in[1];
  const float* conv_w  = (const float*)d_in[2];
  const float* conv_b  = (const float*)d_in[3];
  const float* dt_bias = (const float*)d_in[4];
  const float* A_log   = (const float*)d_in[5];
  const float* Dp      = (const float*)d_in[6];
  const float* norm_w  = (const float*)d_in[7];
  const float* W_out   = (const float*)d_in[8];
  float* out = (float*)d_out;

  // --- workspace overlay (peak 148,176,896 bytes — proven layout) ---
  char* w = (char*)d_ws;
  const size_t OFF_WB   = 0;
  const size_t OFF_Z    = OFF_WB  + (size_t)DPROJ * DMODEL * 2;
  const size_t OFF_XBC  = OFF_Z   + (size_t)ROWS * DINNER * 2;
  const size_t OFF_DTR  = OFF_XBC + (size_t)ROWS * CONVDIM * 2;
  const size_t OFF_CONV = OFF_DTR + (size_t)ROWS * NHEADS * 4;
  const size_t OFF_CS   = OFF_CONV+ (size_t)ROWS * CONVDIM * 2;
  const size_t OFF_WOB  = OFF_WB;
  const size_t OFF_DSP  = OFF_WB + (size_t)DMODEL * DINNER * 2;
  const size_t OFF_CUM  = OFF_DSP + (size_t)ROWS * NHEADS * 4;

  __hip_bfloat16* Win_bf  = (__hip_bfloat16*)(w + OFF_WB);
  __hip_bfloat16* Wout_bf = (__hip_bfloat16*)(w + OFF_WOB);
  __hip_bfloat16* Bz      = (__hip_bfloat16*)(w + OFF_Z);
  __hip_bfloat16* Bx      = (__hip_bfloat16*)(w + OFF_XBC);
  float*          Bd      = (float*)(w + OFF_DTR);
  __hip_bfloat16* Bconv   = (__hip_bfloat16*)(w + OFF_CONV);
  float*          dt_sp   = (float*)(w + OFF_DSP);
  float*          cum     = (float*)(w + OFF_CUM);
  __hip_bfloat16* Bcs     = (__hip_bfloat16*)(w + OFF_CS);
  __hip_bfloat16* u_bf    = (__hip_bfloat16*)(w + OFF_CS);
  __hip_bfloat16* Yraw    = Bx;
  __hip_bfloat16* ybf     = Bcs;

  // 0. casts: W_in + u -> bf16 (one dispatch)
  {
    const int n1 = DPROJ * DMODEL, n2 = ROWS * DMODEL;
    cast2_f32_bf16<<<(n1 + n2) / 4 / 256, 256, 0, stream>>>(W_in, Win_bf, n1, u, u_bf, n2);
  }
  // 1. in-projection
  gemm_tiled<1><<<dim3(ROWS / 128, (DPROJ + 127) / 128), 256, 0, stream>>>(
      (const short*)u_bf, (const short*)Win_bf, Bz, Bx, Bd, nullptr, ROWS, DPROJ, DMODEL);
  // 0b. cast W_out -> bf16 (reuses Win_bf region)
  cast_f32_bf16<<<(DMODEL * DINNER / 4 + 255) / 256, 256, 0, stream>>>(W_out, Wout_bf, DMODEL * DINNER);
  // 2. conv + SiLU
  conv_silu_kernel<<<ROWS * 272 / 256, 256, 0, stream>>>(Bx, conv_w, conv_b, Bconv);
  // 3. dt softplus + cumsum (wave-parallel prefix scan)
  dt_cumsum_kernel<<<BSZ * NHEADS * NCHUNK / 4, 256, 0, stream>>>(
      Bd, dt_bias, A_log, dt_sp, cum);
  // 4. per-chunk states
  chunk_state_kernel<<<dim3(NCHUNK, NHEADS, BSZ), 256, 0, stream>>>(Bconv, dt_sp, cum, Bcs);
  // 5. inter-chunk exclusive scan
  scan_kernel<<<(BSZ * NHEADS * HEADDIM * DSTATE) / 256, 256, 0, stream>>>(Bcs, cum);
  // 6. Y
  y_kernel<<<dim3(NCHUNK, NHEADS, BSZ), 256, 0, stream>>>(Bconv, dt_sp, cum, Bcs, Dp, Yraw);
  // 7. gate + RMSNorm
  gate_norm_kernel<<<ROWS, 256, 0, stream>>>(Yraw, Bz, norm_w, ybf);
  // 8. out-projection
  gemm_tiled<0><<<dim3(ROWS / 128, DMODEL / 128), 256, 0, stream>>>(
      (const short*)ybf, (const short*)Wout_bf, nullptr, nullptr, nullptr, out, ROWS, DMODEL, DINNER);
}

// Round 7
// 392.377 us; speedup vs baseline: 2.6702x; 1.0153x over previous
//
#include <hip/hip_runtime.h>
#include <hip/hip_bf16.h>
#include <math.h>

// ---------------- constants ----------------
#define BSZ     2
#define TLEN    4096
#define DMODEL  1024
#define DINNER  2048
#define DSTATE  64
#define NHEADS  32
#define HEADDIM 64
#define CHUNK   64
#define NCHUNK  64            // TLEN / CHUNK
#define CONVDIM 2176          // DINNER + 2*DSTATE
#define DPROJ   4256          // 2*DINNER + 2*DSTATE + NHEADS
#define ROWS    8192          // BSZ*TLEN
#define LDP     72            // 64 + 8 pad (shorts) for MFMA LDS tiles
#define LDE     136           // 128 + 8 pad (shorts) for gemm epilogue tile

typedef __attribute__((ext_vector_type(8))) short s16x8;
typedef __attribute__((ext_vector_type(4))) short s16x4;
typedef __attribute__((ext_vector_type(4))) float f32x4;

__device__ __forceinline__ float bf2f(__hip_bfloat16 x) { return __bfloat162float(x); }
__device__ __forceinline__ __hip_bfloat16 f2bf(float x) { return __float2bfloat16(x); }
__device__ __forceinline__ short f2bf_s(float x) {
  union { __hip_bfloat16 h; short s; } c; c.h = __float2bfloat16(x); return c.s;
}
__device__ __forceinline__ float s2f(short s) {
  union { unsigned int u; float f; } c; c.u = ((unsigned int)(unsigned short)s) << 16; return c.f;
}
__device__ __forceinline__ s16x8 scale8(s16x8 a, float s) {
  s16x8 r;
#pragma unroll
  for (int i = 0; i < 8; ++i) r[i] = f2bf_s(s2f(a[i]) * s);
  return r;
}

#define GLDS16(g, l)                                                        \
  __builtin_amdgcn_global_load_lds(                                         \
      (const __attribute__((address_space(1))) void*)(g),                   \
      (__attribute__((address_space(3))) void*)(l), 16, 0, 0)

// ---------------- f32 -> bf16 casts ----------------
__global__ __launch_bounds__(256) void cast_f32_bf16(
    const float* __restrict__ src, __hip_bfloat16* __restrict__ dst, int n) {
  const int i = (blockIdx.x * 256 + threadIdx.x) * 4;
  if (i + 3 < n) {
    const f32x4 v = *(const f32x4*)(src + i);
    dst[i + 0] = f2bf(v[0]); dst[i + 1] = f2bf(v[1]);
    dst[i + 2] = f2bf(v[2]); dst[i + 3] = f2bf(v[3]);
  } else {
    for (int j = i; j < n; ++j) dst[j] = f2bf(src[j]);
  }
}

__global__ __launch_bounds__(256) void cast2_f32_bf16(
    const float* __restrict__ s1, __hip_bfloat16* __restrict__ d1, int n1,
    const float* __restrict__ s2, __hip_bfloat16* __restrict__ d2, int n2) {
  const int i = (blockIdx.x * 256 + threadIdx.x) * 4;   // n1, n2 divisible by 4
  if (i < n1) {
    const f32x4 v = *(const f32x4*)(s1 + i);
    d1[i + 0] = f2bf(v[0]); d1[i + 1] = f2bf(v[1]);
    d1[i + 2] = f2bf(v[2]); d1[i + 3] = f2bf(v[3]);
  } else {
    const int j = i - n1;
    if (j < n2) {
      const f32x4 v = *(const f32x4*)(s2 + j);
      d2[j + 0] = f2bf(v[0]); d2[j + 1] = f2bf(v[1]);
      d2[j + 2] = f2bf(v[2]); d2[j + 3] = f2bf(v[3]);
    }
  }
}

// ---------------- LDS-tiled GEMM, BK=64, XOR-swizzled: C = A[M][K] @ B[N][K]^T ----------------
// 128x128 tile, 4 waves each 64x64.
// SPLIT=1 (in-proj): operand-SWAPPED mfma -> acc regs hold 4 consecutive output COLS.
//   Epilogue: pack short4 -> LDS transpose tile -> 16B coalesced stores.
//   n-tiles 0-15 -> z (ld 2048), 16-32 -> xBC (ld 2176), 33 -> dt f32 (scalar path).
// SPLIT=0 (out-proj): unswapped, scalar coalesced f32 dword stores (K=2048 amortizes).
template <int SPLIT>
__global__ __launch_bounds__(256) void gemm_tiled(
    const short* __restrict__ A, const short* __restrict__ B,
    __hip_bfloat16* __restrict__ Cz, __hip_bfloat16* __restrict__ Cx,
    float* __restrict__ Cd, float* __restrict__ Cout, int M, int N, int K) {
  __shared__ __align__(16) short smem[128 * LDE];   // 34.8 KB; staging aliases epilogue tile
  short* sA = smem;                                  // 128*64
  short* sB = smem + 128 * 64;                       // 128*64
  const int tid  = threadIdx.x;
  const int wave = tid >> 6, lane = tid & 63;
  const int lhi  = lane >> 4, llo = lane & 15;
  const int wm   = wave >> 1, wn = wave & 1;
  const int tm   = blockIdx.x * 128, tn = blockIdx.y * 128;

  // staging map: seg covers 8 rows (1 KB); lane i -> row seg*8 + i/8, global chunk (i&7)^(i>>3)
  const int srow = lane >> 3;                 // 0..7
  const int skc  = ((lane & 7) ^ srow) * 8;   // swizzled k-chunk (shorts)

  f32x4 acc[4][4];
  const f32x4 fz = {0.f, 0.f, 0.f, 0.f};
#pragma unroll
  for (int mi = 0; mi < 4; ++mi)
#pragma unroll
    for (int ni = 0; ni < 4; ++ni) acc[mi][ni] = fz;

  for (int k0 = 0; k0 < K; k0 += 64) {
#pragma unroll
    for (int t = 0; t < 4; ++t) {
      const int seg = t * 4 + wave;                      // 0..15
      const int rl  = seg * 8 + srow;
      GLDS16(A + (size_t)(tm + rl) * K + k0 + skc, sA + seg * 512);
      GLDS16(B + (size_t)(tn + rl) * K + k0 + skc, sB + seg * 512);
    }
    __syncthreads();
#pragma unroll
    for (int sub = 0; sub < 2; ++sub) {
      s16x8 af[4], bfr[4];
#pragma unroll
      for (int i = 0; i < 4; ++i) {
        const int am = wm * 64 + i * 16 + llo;
        af[i]  = *(const s16x8*)(sA + am * 64 + ((sub * 4 + lhi) ^ (am & 7)) * 8);
        const int bn = wn * 64 + i * 16 + llo;
        bfr[i] = *(const s16x8*)(sB + bn * 64 + ((sub * 4 + lhi) ^ (bn & 7)) * 8);
      }
#pragma unroll
      for (int mi = 0; mi < 4; ++mi)
#pragma unroll
        for (int ni = 0; ni < 4; ++ni)
          acc[mi][ni] = SPLIT
            ? __builtin_amdgcn_mfma_f32_16x16x32_bf16(bfr[ni], af[mi], acc[mi][ni], 0, 0, 0)
            : __builtin_amdgcn_mfma_f32_16x16x32_bf16(af[mi], bfr[ni], acc[mi][ni], 0, 0, 0);
    }
    __syncthreads();
  }

  if (SPLIT) {
    // swapped layout: out_row = ...+llo, out_col = ...+lhi*4+r (4 consecutive cols per acc)
    if (blockIdx.y < 33) {
      // vectorized path via LDS transpose (region uniform per block)
#pragma unroll
      for (int mi = 0; mi < 4; ++mi)
#pragma unroll
        for (int ni = 0; ni < 4; ++ni) {
          const int rl = wm * 64 + mi * 16 + llo;
          const int cl = wn * 64 + ni * 16 + lhi * 4;
          s16x4 v;
#pragma unroll
          for (int r = 0; r < 4; ++r) v[r] = f2bf_s(acc[mi][ni][r]);
          *(s16x4*)(smem + rl * LDE + cl) = v;
        }
      __syncthreads();
      const int rl = tid >> 1;
      const int ch = (tid & 1) * 64;
      const short* src = smem + rl * LDE + ch;
      short* gp;
      if (blockIdx.y < 16)
        gp = (short*)Cz + (size_t)(tm + rl) * DINNER + tn + ch;
      else
        gp = (short*)Cx + (size_t)(tm + rl) * CONVDIM + (tn - DINNER) + ch;
#pragma unroll
      for (int j = 0; j < 8; ++j)
        *(s16x8*)(gp + j * 8) = *(const s16x8*)(src + j * 8);
    } else {
      // dt tile: cols 4224..4256 valid (local 0..32) -> f32, scalar
#pragma unroll
      for (int mi = 0; mi < 4; ++mi)
#pragma unroll
        for (int ni = 0; ni < 4; ++ni)
#pragma unroll
          for (int r = 0; r < 4; ++r) {
            const int col = wn * 64 + ni * 16 + lhi * 4 + r;
            if (col < NHEADS) {
              const int row = tm + wm * 64 + mi * 16 + llo;
              Cd[(size_t)row * NHEADS + col] = acc[mi][ni][r];
            }
          }
    }
  } else {
#pragma unroll
    for (int mi = 0; mi < 4; ++mi)
#pragma unroll
      for (int ni = 0; ni < 4; ++ni)
#pragma unroll
        for (int r = 0; r < 4; ++r) {
          const int row = tm + wm * 64 + mi * 16 + lhi * 4 + r;
          const int col = tn + wn * 64 + ni * 16 + llo;
          Cout[(size_t)row * N + col] = acc[mi][ni][r];
        }
  }
}

// ---------------- conv1d (depthwise, causal, width 4) + SiLU — vectorized 8 ch/thread ----------------
__global__ __launch_bounds__(256) void conv_silu_kernel(
    const __hip_bfloat16* __restrict__ xBC, const float* __restrict__ conv_w,
    const float* __restrict__ conv_b, __hip_bfloat16* __restrict__ convOut) {
  const int idx8 = blockIdx.x * 256 + threadIdx.x;   // bt*272 + c8
  const int c8 = idx8 % 272;
  const int bt = idx8 / 272;
  if (bt >= ROWS) return;
  const int t = bt & (TLEN - 1);
  const int c = c8 * 8;
  const short* xp = (const short*)xBC;

  f32x4 w4[8];
#pragma unroll
  for (int j = 0; j < 8; ++j) w4[j] = *(const f32x4*)(conv_w + (c + j) * 4);

  float acc[8];
  const f32x4 b0 = *(const f32x4*)(conv_b + c);
  const f32x4 b1 = *(const f32x4*)(conv_b + c + 4);
#pragma unroll
  for (int j = 0; j < 4; ++j) { acc[j] = b0[j]; acc[4 + j] = b1[j]; }

#pragma unroll
  for (int k = 0; k < 4; ++k) {
    const int tt = t - 3 + k;
    if (tt < 0) continue;
    const s16x8 xv = *(const s16x8*)(xp + (size_t)(bt - 3 + k) * CONVDIM + c);
#pragma unroll
    for (int j = 0; j < 8; ++j) acc[j] += w4[j][k] * s2f(xv[j]);
  }
  s16x8 o;
#pragma unroll
  for (int j = 0; j < 8; ++j) {
    const float s = acc[j] / (1.f + expf(-acc[j]));
    o[j] = f2bf_s(s);
  }
  *(s16x8*)((short*)convOut + (size_t)bt * CONVDIM + c) = o;
}

// ---------------- dt softplus + per-chunk cumsum of A*dt — one wave per (b,h,chunk) ----------------
__global__ __launch_bounds__(256) void dt_cumsum_kernel(
    const float* __restrict__ dt_raw, const float* __restrict__ dt_bias,
    const float* __restrict__ A_log, float* __restrict__ dt_sp, float* __restrict__ cum) {
  const int lane = threadIdx.x & 63;
  const int w = blockIdx.x * 4 + (threadIdx.x >> 6);   // bh*64 + c
  const int c = w & 63, bh = w >> 6;
  const int h = bh & 31, b = bh >> 5;
  const int t = c * CHUNK + lane;
  const float raw = dt_raw[((size_t)(b * TLEN + t)) * NHEADS + h] + dt_bias[h];
  const float d = (raw > 20.f) ? raw : log1pf(expf(raw));
  float v = -expf(A_log[h]) * d;
#pragma unroll
  for (int off = 1; off < 64; off <<= 1) {
    const float nb = __shfl_up(v, off, 64);
    if (lane >= off) v += nb;
  }
  dt_sp[(size_t)bh * TLEN + t] = d;
  cum[(size_t)bh * TLEN + t] = v;
}

// ---------------- per-chunk state (MFMA): cs[p][n] = sum_l xd[l][p]*B[l][n] ----------------
__global__ __launch_bounds__(256) void chunk_state_kernel(
    const __hip_bfloat16* __restrict__ convOut, const float* __restrict__ dt_sp,
    const float* __restrict__ cum, __hip_bfloat16* __restrict__ chunk_states) {
  __shared__ __align__(16) short sBT [64 * LDP];   // B^T [n][l]
  __shared__ __align__(16) short sXdT[64 * LDP];   // xd^T [p][l]
  const int c = blockIdx.x, h = blockIdx.y, b = blockIdx.z;
  const int tid = threadIdx.x;
  const int wave = tid >> 6, lane = tid & 63;
  const int lhi = lane >> 4, llo = lane & 15;
  const int bh = b * NHEADS + h;
  const float cumL = cum[(size_t)bh * TLEN + c * CHUNK + 63];
  const short* cOut = (const short*)convOut;

  for (int v = tid; v < 512; v += 256) {
    const int l = v >> 3, ch = v & 7;
    const size_t rowoff = ((size_t)(b * TLEN + c * CHUNK + l)) * CONVDIM;
    const s16x8 bv = *(const s16x8*)(cOut + rowoff + DINNER + ch * 8);
    const float wgt = dt_sp[(size_t)bh * TLEN + c * CHUNK + l] *
                      expf(cumL - cum[(size_t)bh * TLEN + c * CHUNK + l]);
    const s16x8 xv = *(const s16x8*)(cOut + rowoff + h * HEADDIM + ch * 8);
#pragma unroll
    for (int jj = 0; jj < 8; ++jj) {
      sBT [(ch * 8 + jj) * LDP + l] = bv[jj];
      sXdT[(ch * 8 + jj) * LDP + l] = f2bf_s(s2f(xv[jj]) * wgt);
    }
  }
  __syncthreads();

  const f32x4 fz = {0.f, 0.f, 0.f, 0.f};
  const s16x8 a0 = *(const s16x8*)(sXdT + (16 * wave + llo) * LDP + lhi * 8);
  const s16x8 a1 = *(const s16x8*)(sXdT + (16 * wave + llo) * LDP + 32 + lhi * 8);
  const size_t outb = ((((size_t)b * NCHUNK + c) * NHEADS + h) * HEADDIM) * DSTATE;
#pragma unroll
  for (int j = 0; j < 4; ++j) {
    const s16x8 b0 = *(const s16x8*)(sBT + (16 * j + llo) * LDP + lhi * 8);
    const s16x8 b1 = *(const s16x8*)(sBT + (16 * j + llo) * LDP + 32 + lhi * 8);
    f32x4 acc = fz;
    acc = __builtin_amdgcn_mfma_f32_16x16x32_bf16(a0, b0, acc, 0, 0, 0);
    acc = __builtin_amdgcn_mfma_f32_16x16x32_bf16(a1, b1, acc, 0, 0, 0);
#pragma unroll
    for (int r = 0; r < 4; ++r) {
      const int p = 16 * wave + lhi * 4 + r;
      const int n = 16 * j + llo;
      chunk_states[outb + (size_t)p * DSTATE + n] = f2bf(acc[r]);
    }
  }
}

// ---------------- inter-chunk scan, IN-PLACE ----------------
__global__ __launch_bounds__(256) void scan_kernel(
    __hip_bfloat16* __restrict__ cs, const float* __restrict__ cum) {
  const int idx = blockIdx.x * 256 + threadIdx.x;
  const int n = idx & 63;
  int r = idx >> 6;
  const int p = r & 63; r >>= 6;
  const int h = r & 31;
  const int b = r >> 5;
  const int bh = b * NHEADS + h;
  const size_t stride_c = (size_t)NHEADS * HEADDIM * DSTATE;
  const size_t base = ((size_t)b * NCHUNK) * stride_c + ((size_t)h * HEADDIM + p) * DSTATE + n;
  float s = 0.f;
  for (int c = 0; c < NCHUNK; ++c) {
    const size_t off = base + (size_t)c * stride_c;
    const float val = bf2f(cs[off]);
    cs[off] = f2bf(s);
    const float dec = expf(cum[(size_t)bh * TLEN + c * CHUNK + 63]);
    s = dec * s + val;
  }
}

// ---------------- per-chunk output (MFMA) ----------------
__global__ __launch_bounds__(256) void y_kernel(
    const __hip_bfloat16* __restrict__ convOut, const float* __restrict__ dt_sp,
    const float* __restrict__ cum, const __hip_bfloat16* __restrict__ states_pre,
    const float* __restrict__ Dparam, __hip_bfloat16* __restrict__ Yraw) {
  __shared__ __align__(16) short sC [64 * LDP];   // C[l][n]
  __shared__ __align__(16) short sBW[64 * LDP];   // phase1: B[s][n]; phase3: W[l][s]
  __shared__ __align__(16) short sXT[64 * LDP];   // xdt^T [p][s]
  __shared__ __align__(16) short sSP[64 * LDP];   // SP[p][n]
  __shared__ float scum[64];
  const int c = blockIdx.x, h = blockIdx.y, b = blockIdx.z;
  const int tid = threadIdx.x;
  const int wave = tid >> 6, lane = tid & 63;
  const int lhi = lane >> 4, llo = lane & 15;
  const int bh = b * NHEADS + h;
  const size_t tbase = (size_t)(b * TLEN + c * CHUNK);
  const short* cOut = (const short*)convOut;
  const size_t spbase = ((((size_t)b * NCHUNK + c) * NHEADS + h) * HEADDIM) * DSTATE;
  const f32x4 fz = {0.f, 0.f, 0.f, 0.f};

  for (int v = tid; v < 512; v += 256) {
    const int r = v >> 3, ch = v & 7;
    const size_t rowoff = (tbase + r) * CONVDIM;
    *(s16x8*)(sC  + r * LDP + ch * 8) = *(const s16x8*)(cOut + rowoff + DINNER + DSTATE + ch * 8);
    *(s16x8*)(sBW + r * LDP + ch * 8) = *(const s16x8*)(cOut + rowoff + DINNER + ch * 8);
    *(s16x8*)(sSP + r * LDP + ch * 8) = *(const s16x8*)((const short*)states_pre + spbase + r * 64 + ch * 8);
    const float dt = dt_sp[(size_t)bh * TLEN + c * CHUNK + r];
    const s16x8 xv = *(const s16x8*)(cOut + rowoff + h * HEADDIM + ch * 8);
#pragma unroll
    for (int jj = 0; jj < 8; ++jj)
      sXT[(ch * 8 + jj) * LDP + r] = f2bf_s(s2f(xv[jj]) * dt);
  }
  if (tid < 64) scum[tid] = cum[(size_t)bh * TLEN + c * CHUNK + tid];
  __syncthreads();

  // phase 1: G[l][s]
  const s16x8 aC0 = *(const s16x8*)(sC + (16 * wave + llo) * LDP + lhi * 8);
  const s16x8 aC1 = *(const s16x8*)(sC + (16 * wave + llo) * LDP + 32 + lhi * 8);
  f32x4 g[4];
#pragma unroll
  for (int j = 0; j < 4; ++j) {
    const s16x8 b0 = *(const s16x8*)(sBW + (16 * j + llo) * LDP + lhi * 8);
    const s16x8 b1 = *(const s16x8*)(sBW + (16 * j + llo) * LDP + 32 + lhi * 8);
    f32x4 acc = fz;
    acc = __builtin_amdgcn_mfma_f32_16x16x32_bf16(aC0, b0, acc, 0, 0, 0);
    acc = __builtin_amdgcn_mfma_f32_16x16x32_bf16(aC1, b1, acc, 0, 0, 0);
    g[j] = acc;
  }
  __syncthreads();

  // phase 2: W[l][s] = (s<=l) ? G*exp(cum[l]-cum[s]) : 0
  float cl[4];
#pragma unroll
  for (int r = 0; r < 4; ++r) cl[r] = scum[16 * wave + lhi * 4 + r];
#pragma unroll
  for (int j = 0; j < 4; ++j) {
    const int s = 16 * j + llo;
    const float cs_ = scum[s];
#pragma unroll
    for (int r = 0; r < 4; ++r) {
      const int l = 16 * wave + lhi * 4 + r;
      const float v = (s <= l) ? g[j][r] * expf(cl[r] - cs_) : 0.f;
      sBW[l * LDP + s] = f2bf_s(v);
    }
  }
  __syncthreads();

  // phase 3: Y[l][p]
  const float el = expf(scum[16 * wave + llo]);
  const s16x8 aCs0 = scale8(aC0, el);
  const s16x8 aCs1 = scale8(aC1, el);
  const s16x8 aW0 = *(const s16x8*)(sBW + (16 * wave + llo) * LDP + lhi * 8);
  const s16x8 aW1 = *(const s16x8*)(sBW + (16 * wave + llo) * LDP + 32 + lhi * 8);
  const float Dh = Dparam[h];
#pragma unroll
  for (int j = 0; j < 4; ++j) {
    const s16x8 bx0 = *(const s16x8*)(sXT + (16 * j + llo) * LDP + lhi * 8);
    const s16x8 bx1 = *(const s16x8*)(sXT + (16 * j + llo) * LDP + 32 + lhi * 8);
    const s16x8 bs0 = *(const s16x8*)(sSP + (16 * j + llo) * LDP + lhi * 8);
    const s16x8 bs1 = *(const s16x8*)(sSP + (16 * j + llo) * LDP + 32 + lhi * 8);
    f32x4 acc = fz;
    acc = __builtin_amdgcn_mfma_f32_16x16x32_bf16(aW0, bx0, acc, 0, 0, 0);
    acc = __builtin_amdgcn_mfma_f32_16x16x32_bf16(aW1, bx1, acc, 0, 0, 0);
    acc = __builtin_amdgcn_mfma_f32_16x16x32_bf16(aCs0, bs0, acc, 0, 0, 0);
    acc = __builtin_amdgcn_mfma_f32_16x16x32_bf16(aCs1, bs1, acc, 0, 0, 0);
#pragma unroll
    for (int r = 0; r < 4; ++r) {
      const int l = 16 * wave + lhi * 4 + r;
      const int p = 16 * j + llo;
      const size_t row = tbase + l;
      const float xval = bf2f(convOut[row * CONVDIM + h * HEADDIM + p]);
      Yraw[row * DINNER + h * HEADDIM + p] = f2bf(acc[r] + Dh * xval);
    }
  }
}

// ---------------- gate (silu(z)) + RMSNorm -> bf16 ----------------
__global__ __launch_bounds__(256) void gate_norm_kernel(
    const __hip_bfloat16* __restrict__ Yraw, const __hip_bfloat16* __restrict__ z,
    const float* __restrict__ norm_w, __hip_bfloat16* __restrict__ ybf) {
  const int row = blockIdx.x;
  const int tid = threadIdx.x;
  const size_t base = (size_t)row * DINNER + tid * 8;
  const s16x8 yv8 = *(const s16x8*)((const short*)Yraw + base);
  const s16x8 zv8 = *(const s16x8*)((const short*)z + base);
  float vals[8];
  float ss = 0.f;
#pragma unroll
  for (int j = 0; j < 8; ++j) {
    const float zv = s2f(zv8[j]);
    const float v = s2f(yv8[j]) * (zv / (1.f + expf(-zv)));
    vals[j] = v;
    ss += v * v;
  }
#pragma unroll
  for (int off = 32; off > 0; off >>= 1) ss += __shfl_down(ss, off, 64);
  __shared__ float red[4];
  if ((tid & 63) == 0) red[tid >> 6] = ss;
  __syncthreads();
  const float rms = rsqrtf((red[0] + red[1] + red[2] + red[3]) / (float)DINNER + 1e-5f);
  const f32x4 nw0 = *(const f32x4*)(norm_w + tid * 8);
  const f32x4 nw1 = *(const f32x4*)(norm_w + tid * 8 + 4);
  s16x8 o;
#pragma unroll
  for (int j = 0; j < 4; ++j) {
    o[j]     = f2bf_s(vals[j] * rms * nw0[j]);
    o[4 + j] = f2bf_s(vals[4 + j] * rms * nw1[j]);
  }
  *(s16x8*)((short*)ybf + base) = o;
}

// ---------------- launch ----------------
extern "C" void kernel_launch(void* const* d_in, const int* in_sizes, int n_in,
                              void* d_out, int out_size, void* d_ws, size_t ws_size,
                              hipStream_t stream) {
  const float* u       = (const float*)d_in[0];
  const float* W_in    = (const float*)d_in[1];
  const float* conv_w  = (const float*)d_in[2];
  const float* conv_b  = (const float*)d_in[3];
  const float* dt_bias = (const float*)d_in[4];
  const float* A_log   = (const float*)d_in[5];
  const float* Dp      = (const float*)d_in[6];
  const float* norm_w  = (const float*)d_in[7];
  const float* W_out   = (const float*)d_in[8];
  float* out = (float*)d_out;

  // --- workspace overlay (peak 148,176,896 bytes — proven layout) ---
  char* w = (char*)d_ws;
  const size_t OFF_WB   = 0;
  const size_t OFF_Z    = OFF_WB  + (size_t)DPROJ * DMODEL * 2;
  const size_t OFF_XBC  = OFF_Z   + (size_t)ROWS * DINNER * 2;
  const size_t OFF_DTR  = OFF_XBC + (size_t)ROWS * CONVDIM * 2;
  const size_t OFF_CONV = OFF_DTR + (size_t)ROWS * NHEADS * 4;
  const size_t OFF_CS   = OFF_CONV+ (size_t)ROWS * CONVDIM * 2;
  const size_t OFF_WOB  = OFF_WB;
  const size_t OFF_DSP  = OFF_WB + (size_t)DMODEL * DINNER * 2;
  const size_t OFF_CUM  = OFF_DSP + (size_t)ROWS * NHEADS * 4;

  __hip_bfloat16* Win_bf  = (__hip_bfloat16*)(w + OFF_WB);
  __hip_bfloat16* Wout_bf = (__hip_bfloat16*)(w + OFF_WOB);
  __hip_bfloat16* Bz      = (__hip_bfloat16*)(w + OFF_Z);
  __hip_bfloat16* Bx      = (__hip_bfloat16*)(w + OFF_XBC);
  float*          Bd      = (float*)(w + OFF_DTR);
  __hip_bfloat16* Bconv   = (__hip_bfloat16*)(w + OFF_CONV);
  float*          dt_sp   = (float*)(w + OFF_DSP);
  float*          cum     = (float*)(w + OFF_CUM);
  __hip_bfloat16* Bcs     = (__hip_bfloat16*)(w + OFF_CS);
  __hip_bfloat16* u_bf    = (__hip_bfloat16*)(w + OFF_CS);
  __hip_bfloat16* Yraw    = Bx;
  __hip_bfloat16* ybf     = Bcs;

  // 0. casts: W_in + u -> bf16 (one dispatch)
  {
    const int n1 = DPROJ * DMODEL, n2 = ROWS * DMODEL;
    cast2_f32_bf16<<<(n1 + n2) / 4 / 256, 256, 0, stream>>>(W_in, Win_bf, n1, u, u_bf, n2);
  }
  // 1. in-projection
  gemm_tiled<1><<<dim3(ROWS / 128, (DPROJ + 127) / 128), 256, 0, stream>>>(
      (const short*)u_bf, (const short*)Win_bf, Bz, Bx, Bd, nullptr, ROWS, DPROJ, DMODEL);
  // 0b. cast W_out -> bf16 (reuses Win_bf region)
  cast_f32_bf16<<<(DMODEL * DINNER / 4 + 255) / 256, 256, 0, stream>>>(W_out, Wout_bf, DMODEL * DINNER);
  // 2. conv + SiLU
  conv_silu_kernel<<<ROWS * 272 / 256, 256, 0, stream>>>(Bx, conv_w, conv_b, Bconv);
  // 3. dt softplus + cumsum (wave-parallel prefix scan)
  dt_cumsum_kernel<<<BSZ * NHEADS * NCHUNK / 4, 256, 0, stream>>>(
      Bd, dt_bias, A_log, dt_sp, cum);
  // 4. per-chunk states
  chunk_state_kernel<<<dim3(NCHUNK, NHEADS, BSZ), 256, 0, stream>>>(Bconv, dt_sp, cum, Bcs);
  // 5. inter-chunk exclusive scan
  scan_kernel<<<(BSZ * NHEADS * HEADDIM * DSTATE) / 256, 256, 0, stream>>>(Bcs, cum);
  // 6. Y
  y_kernel<<<dim3(NCHUNK, NHEADS, BSZ), 256, 0, stream>>>(Bconv, dt_sp, cum, Bcs, Dp, Yraw);
  // 7. gate + RMSNorm
  gate_norm_kernel<<<ROWS, 256, 0, stream>>>(Yraw, Bz, norm_w, ybf);
  // 8. out-projection
  gemm_tiled<0><<<dim3(ROWS / 128, DMODEL / 128), 256, 0, stream>>>(
      (const short*)ybf, (const short*)Wout_bf, nullptr, nullptr, nullptr, out, ROWS, DMODEL, DINNER);
}